// Round 14
// baseline (338.012 us; speedup 1.0000x reference)
//
#include <hip/hip_runtime.h>
#include <hip/hip_fp16.h>

// Node_Embedding: HeteroGraphConv(sum) of 4 GraphConv relations + PReLU.
// GEMM commuted BEFORE the gather: y_rel = coef_rel ⊙ (x @ W_rel) (fp16,
// MFMA), then out[d] = prelu(Σ_rel dinv_rel·Σ_e y_rel[src] + Σb). Gather
// writes the final fp32 row once (512B contiguous) — avoids the 9x write
// amplification seen with split half-row agg writes (R13: 474MB vs 51MB).
// CSR build: chunked LDS histograms + chunked LDS-cursor counting sort
// (no global atomics, no memsets). Edge payload: u16 src only (4 MB).

#define NB 50000   // nodes per type
#define EB 500000  // edges per relation
#define D  128
#define NCH 98     // ceil(NB/512)
#define CAP 512    // gather LDS edge-window capacity per relation (mean 160)
#define NCHK 16    // edge chunks
#define CH2 15625  // (EB/NCHK)/2 int2 loads per chunk
#define NRG 8      // node ranges
#define FR 6250    // nodes per range

struct EdgePtrs { const int* src[4]; const int* dst[4]; };

typedef _Float16 f16x8 __attribute__((ext_vector_type(8)));
typedef float f32x4 __attribute__((ext_vector_type(4)));

__device__ inline float hlo(unsigned u) {
    return __half2float(__ushort_as_half((unsigned short)(u & 0xffffu)));
}
__device__ inline float hhi(unsigned u) {
    return __half2float(__ushort_as_half((unsigned short)(u >> 16)));
}

// Chunked LDS histogram. Block (chunk, range, z) with z = io*4 + rel.
__global__ __launch_bounds__(256) void k_hist(EdgePtrs ep,
                                              unsigned short* __restrict__ cnt2in,
                                              unsigned short* __restrict__ cnt2o) {
    __shared__ unsigned pk[FR / 2];   // packed u16 pairs, 12.5 KB
    const int chunk = blockIdx.x, range = blockIdx.y;
    const int rel = blockIdx.z & 3, io = blockIdx.z >> 2;
    const int lo = range * FR;
    const int* arr = io ? ep.src[rel] : ep.dst[rel];
    for (int i = threadIdx.x; i < FR / 2; i += 256) pk[i] = 0;
    __syncthreads();
    const int2* a2 = reinterpret_cast<const int2*>(arr) + (size_t)chunk * CH2;
    for (int i = threadIdx.x; i < CH2; i += 256) {
        int2 v = a2[i];
        int n0 = v.x - lo;
        if ((unsigned)n0 < (unsigned)FR) atomicAdd(&pk[n0 >> 1], 1u << (16 * (n0 & 1)));
        int n1 = v.y - lo;
        if ((unsigned)n1 < (unsigned)FR) atomicAdd(&pk[n1 >> 1], 1u << (16 * (n1 & 1)));
    }
    __syncthreads();
    unsigned short* out = io ? cnt2o : cnt2in;
    unsigned* dst = reinterpret_cast<unsigned*>(out + ((size_t)(rel * NCHK + chunk)) * NB);
    for (int i = threadIdx.x; i < FR / 2; i += 256) dst[lo / 2 + i] = pk[i];
}

// Pack W (fp32 [4][128][128]) -> MFMA B-fragments fp16: [rel][jt][ks][lane][8].
__global__ __launch_bounds__(256) void k_wpack(const float* __restrict__ W,
                                               _Float16* __restrict__ Wb) {
    int idx = blockIdx.x * 256 + threadIdx.x;   // 8192 total
    int rel = idx >> 11, jt = (idx >> 8) & 7, ks = (idx >> 6) & 3, l = idx & 63;
    int col = jt * 16 + (l & 15);
    int kb = ks * 32 + (l >> 4) * 8;
    _Float16 h[8];
#pragma unroll
    for (int m = 0; m < 8; ++m)
        h[m] = (_Float16)W[rel * D * D + (kb + m) * D + col];
    *reinterpret_cast<f16x8*>(Wb + (size_t)idx * 8) = *reinterpret_cast<f16x8*>(h);
}

// Phase 1: per node — chunk-prefix cnt2in in place (u16), outdeg -> coef,
// then per-512-node exclusive block scan of total in-degree.
__global__ __launch_bounds__(512) void k_scan1(unsigned short* __restrict__ cnt2in,
                                               const unsigned short* __restrict__ cnt2o,
                                               float* __restrict__ coef,
                                               int* __restrict__ offs,
                                               int* __restrict__ chunksum) {
    int r = blockIdx.y, c = blockIdx.x, t = threadIdx.x;
    int node = c * 512 + t;
    int v = 0;
    if (node < NB) {
        int tin = 0;
#pragma unroll
        for (int k = 0; k < NCHK; ++k) {
            size_t idx = ((size_t)(r * NCHK + k)) * NB + node;
            int cc = cnt2in[idx];
            cnt2in[idx] = (unsigned short)tin;   // exclusive chunk prefix
            tin += cc;
        }
        v = tin;
        int tout = 0;
#pragma unroll
        for (int k = 0; k < NCHK; ++k)
            tout += cnt2o[((size_t)(r * NCHK + k)) * NB + node];
        coef[r * NB + node] = rsqrtf((float)(tout > 1 ? tout : 1));
    }
    __shared__ int sh[512];
    sh[t] = v;
    __syncthreads();
    for (int off = 1; off < 512; off <<= 1) {
        int u = (t >= off) ? sh[t - off] : 0;
        __syncthreads();
        sh[t] += u;
        __syncthreads();
    }
    int incl = sh[t];
    if (node < NB) offs[r * (NB + 1) + node] = incl - v;  // local exclusive
    if (t == 511) chunksum[r * NCH + c] = incl;
}

// Phase 2: exclusive scan of the NCH chunk totals per relation (wave r).
__global__ __launch_bounds__(256) void k_scan2(int* __restrict__ chunksum) {
    int r = threadIdx.x >> 6, lane = threadIdx.x & 63;
    int* cs = chunksum + r * NCH;
    int s0 = cs[lane];
    int s1 = (64 + lane < NCH) ? cs[64 + lane] : 0;
    int x = s0;
    for (int d = 1; d < 64; d <<= 1) { int u = __shfl_up(x, d, 64); if (lane >= d) x += u; }
    int tot0 = __shfl(x, 63, 64);
    int y = s1;
    for (int d = 1; d < 64; d <<= 1) { int u = __shfl_up(y, d, 64); if (lane >= d) y += u; }
    y += tot0;
    cs[lane] = x - s0;
    if (64 + lane < NCH) cs[64 + lane] = y - s1;
}

// Phase 3: add chunk base; offs[NB] = EB.
__global__ __launch_bounds__(512) void k_scan3(int* __restrict__ offs,
                                               const int* __restrict__ chunksum) {
    int r = blockIdx.y, c = blockIdx.x, t = threadIdx.x;
    int node = c * 512 + t;
    if (node < NB)
        offs[r * (NB + 1) + node] += chunksum[r * NCH + c];
    if (c == NCH - 1 && t == 0) offs[r * (NB + 1) + NB] = EB;
}

// Chunked counting-sort placement: u16 src payload only.
__global__ __launch_bounds__(256) void k_fill3(EdgePtrs ep,
                                               const unsigned short* __restrict__ cnt2in,
                                               const int* __restrict__ offs,
                                               unsigned short* __restrict__ esrc) {
    __shared__ int cur[FR];           // 25 KB
    const int chunk = blockIdx.x, range = blockIdx.y, rel = blockIdx.z;
    const int lo = range * FR;
    const unsigned short* pre = cnt2in + ((size_t)(rel * NCHK + chunk)) * NB;
    for (int i = threadIdx.x; i < FR; i += 256)
        cur[i] = offs[rel * (NB + 1) + lo + i] + pre[lo + i];
    __syncthreads();
    const int2* d2p = reinterpret_cast<const int2*>(ep.dst[rel]) + (size_t)chunk * CH2;
    const int2* s2p = reinterpret_cast<const int2*>(ep.src[rel]) + (size_t)chunk * CH2;
    unsigned short* er = esrc + (size_t)rel * EB;
    for (int i = threadIdx.x; i < CH2; i += 256) {
        int2 d2 = d2p[i];
        int2 s2 = s2p[i];
        int n0 = d2.x - lo;
        if ((unsigned)n0 < (unsigned)FR) {
            int pos = atomicAdd(&cur[n0], 1);
            er[pos] = (unsigned short)s2.x;
        }
        int n1 = d2.y - lo;
        if ((unsigned)n1 < (unsigned)FR) {
            int pos = atomicAdd(&cur[n1], 1);
            er[pos] = (unsigned short)s2.y;
        }
    }
}

// y_rel = coef_rel ⊙ (x_srctype @ W_rel), fp16 out. MFMA 16x16x32.
__global__ __launch_bounds__(256) void k_ygemm(
    const float* __restrict__ xd, const float* __restrict__ xs,
    const _Float16* __restrict__ Wb, const float* __restrict__ coef,
    _Float16* __restrict__ y) {
    const int rel = blockIdx.y;
    const float* x = (rel < 2) ? xd : xs;   // rel 0,1 src drug; 2,3 src dis
    const int tid = threadIdx.x, w = tid >> 6, l = tid & 63;
    const int rbase = blockIdx.x * 64 + w * 16;
    int arow = rbase + (l & 15); if (arow > NB - 1) arow = NB - 1;
    const int lk = (l >> 4) * 8;
    f32x4 acc[8] = {};
    const f16x8* wb = reinterpret_cast<const f16x8*>(Wb) + (size_t)rel * 32 * 64;
#pragma unroll
    for (int ks = 0; ks < 4; ++ks) {
        float4 x0 = *reinterpret_cast<const float4*>(x + (size_t)arow * D + ks * 32 + lk);
        float4 x1 = *reinterpret_cast<const float4*>(x + (size_t)arow * D + ks * 32 + lk + 4);
        _Float16 af[8] = {(_Float16)x0.x, (_Float16)x0.y, (_Float16)x0.z, (_Float16)x0.w,
                          (_Float16)x1.x, (_Float16)x1.y, (_Float16)x1.z, (_Float16)x1.w};
        f16x8 a = *reinterpret_cast<f16x8*>(af);
#pragma unroll
        for (int jt = 0; jt < 8; ++jt) {
            f16x8 bf = wb[(jt * 4 + ks) * 64 + l];
            acc[jt] = __builtin_amdgcn_mfma_f32_16x16x32_f16(a, bf, acc[jt], 0, 0, 0);
        }
    }
    const int rowoff = (l >> 4) * 4;
#pragma unroll
    for (int m = 0; m < 4; ++m) {
        int grow = rbase + rowoff + m;
        if (grow < NB) {
            float cf = coef[rel * NB + grow];
            _Float16* yr = y + ((size_t)rel * NB + grow) * D;
#pragma unroll
            for (int jt = 0; jt < 8; ++jt)
                yr[jt * 16 + (l & 15)] = (_Float16)(acc[jt][m] * cf);
        }
    }
}

#define PREF(ii, c0, c1, c2, c3, r0, r1, r2, r3)                               \
    {                                                                          \
        int j1 = (ii) + 1 < ghi ? (ii) + 1 : ghi - 1;                          \
        int j2 = (ii) + 2 < ghi ? (ii) + 2 : ghi - 1;                          \
        int j3 = (ii) + 3 < ghi ? (ii) + 3 : ghi - 1;                          \
        unsigned s0 = eb[(ii)], s1 = eb[j1], s2 = eb[j2], s3 = eb[j3];         \
        c0 = 1.f;                                                              \
        c1 = ((ii) + 1 < ghi) ? 1.f : 0.f;                                     \
        c2 = ((ii) + 2 < ghi) ? 1.f : 0.f;                                     \
        c3 = ((ii) + 3 < ghi) ? 1.f : 0.f;                                     \
        r0 = *reinterpret_cast<const uint4*>(x + (s0 * D + cbase));            \
        r1 = *reinterpret_cast<const uint4*>(x + (s1 * D + cbase));            \
        r2 = *reinterpret_cast<const uint4*>(x + (s2 * D + cbase));            \
        r3 = *reinterpret_cast<const uint4*>(x + (s3 * D + cbase));            \
    }

#define FMA8(c, r)                                                             \
    {                                                                          \
        acc[0] = fmaf(hlo(r.x), c, acc[0]); acc[1] = fmaf(hhi(r.x), c, acc[1]);\
        acc[2] = fmaf(hlo(r.y), c, acc[2]); acc[3] = fmaf(hhi(r.y), c, acc[3]);\
        acc[4] = fmaf(hlo(r.z), c, acc[4]); acc[5] = fmaf(hhi(r.z), c, acc[5]);\
        acc[6] = fmaf(hlo(r.w), c, acc[6]); acc[7] = fmaf(hhi(r.w), c, acc[7]);\
    }

// Gather-accumulate over y rows + fused dinv/bias/PReLU epilogue; writes the
// final fp32 out row once (512B contiguous per row). 6 blocks/CU (R8 lesson).
__global__ __launch_bounds__(256, 6) void k_gather(
    const unsigned short* __restrict__ y16,   // y as raw u16, [4][NB][D]
    const int* __restrict__ offs, const unsigned short* __restrict__ esrc,
    const float* __restrict__ b, const float* __restrict__ prelu_a,
    float* __restrict__ out) {
    __shared__ unsigned short ebuf[2][CAP];
    __shared__ int soff[2][17];
    const int t = blockIdx.y;
    const int row0 = blockIdx.x * 16;
    const int tid = threadIdx.x;
    const int g = tid >> 4, l16 = tid & 15;
    const int cbase = l16 * 8;          // this lane's 8 columns

    if (tid < 34) {
        int h = tid / 17, k = tid % 17;
        int rel = h ? (2 + t) : t;
        soff[h][k] = offs[rel * (NB + 1) + row0 + k];
    }
    __syncthreads();

    // stage both relations' edge windows (first CAP each)
    for (int h = 0; h < 2; ++h) {
        int rel = h ? (2 + t) : t;
        const unsigned short* er = esrc + (size_t)rel * EB;
        int base = soff[h][0];
        int tot = soff[h][16] - base; if (tot > CAP) tot = CAP;
        for (int i = tid; i < tot; i += 256) ebuf[h][i] = er[base + i];
    }
    __syncthreads();

    float racc[8] = {0.f, 0.f, 0.f, 0.f, 0.f, 0.f, 0.f, 0.f};
    for (int h = 0; h < 2; ++h) {
        int rel = h ? (2 + t) : t;
        const unsigned short* x = y16 + (size_t)rel * NB * D;
        const unsigned short* er = esrc + (size_t)rel * EB;
        const int base = soff[h][0];
        const int glo = soff[h][g] - base;
        const int ghi0 = soff[h][g + 1] - base;
        const int ghi = ghi0 < CAP ? ghi0 : CAP;   // LDS-resident part
        const unsigned short* eb = ebuf[h];
        float acc[8] = {0.f, 0.f, 0.f, 0.f, 0.f, 0.f, 0.f, 0.f};

        if (glo < ghi) {
            uint4 rA0, rA1, rA2, rA3, rB0, rB1, rB2, rB3;
            float cA0, cA1, cA2, cA3, cB0, cB1, cB2, cB3;
            PREF(glo, cA0, cA1, cA2, cA3, rA0, rA1, rA2, rA3);
            for (int i = glo; i < ghi; i += 8) {
                bool hasB = (i + 4 < ghi);
                if (hasB) PREF(i + 4, cB0, cB1, cB2, cB3, rB0, rB1, rB2, rB3);
                FMA8(cA0, rA0); FMA8(cA1, rA1); FMA8(cA2, rA2); FMA8(cA3, rA3);
                if (i + 8 < ghi) PREF(i + 8, cA0, cA1, cA2, cA3, rA0, rA1, rA2, rA3);
                if (hasB) { FMA8(cB0, rB0); FMA8(cB1, rB1); FMA8(cB2, rB2); FMA8(cB3, rB3); }
            }
        }
        // rare overflow tail straight from global
        for (int i = (glo > CAP ? glo : CAP); i < ghi0; ++i) {
            unsigned si = er[base + i];
            uint4 rr = *reinterpret_cast<const uint4*>(x + (si * D + cbase));
            FMA8(1.f, rr);
        }
        int dg = ghi0 - glo;
        float di = rsqrtf((float)(dg > 1 ? dg : 1));
#pragma unroll
        for (int j = 0; j < 8; ++j) racc[j] = fmaf(acc[j], di, racc[j]);
    }

    // epilogue: bias + PReLU, single 512B-contiguous fp32 row store
    float pa = prelu_a[0];
    const float* bA = b + t * D;
    const float* bB = b + (2 + t) * D;
    float v[8];
#pragma unroll
    for (int j = 0; j < 8; ++j) {
        float s = racc[j] + bA[cbase + j] + bB[cbase + j];
        v[j] = s >= 0.f ? s : pa * s;
    }
    float* o = out + ((size_t)(t * NB + row0 + g)) * D + cbase;
    *reinterpret_cast<float4*>(o)     = make_float4(v[0], v[1], v[2], v[3]);
    *reinterpret_cast<float4*>(o + 4) = make_float4(v[4], v[5], v[6], v[7]);
}

extern "C" void kernel_launch(void* const* d_in, const int* in_sizes, int n_in,
                              void* d_out, int out_size, void* d_ws, size_t ws_size,
                              hipStream_t stream) {
    const float* x_drug = (const float*)d_in[0];
    const float* x_dis  = (const float*)d_in[1];
    const float* W      = (const float*)d_in[2];   // [4,128,128]
    const float* b      = (const float*)d_in[3];   // [4,128]
    const float* pa     = (const float*)d_in[4];   // [1]
    EdgePtrs ep;
    ep.src[0] = (const int*)d_in[5];  ep.dst[0] = (const int*)d_in[6];   // dd
    ep.src[1] = (const int*)d_in[7];  ep.dst[1] = (const int*)d_in[8];   // ds
    ep.src[2] = (const int*)d_in[9];  ep.dst[2] = (const int*)d_in[10];  // sd
    ep.src[3] = (const int*)d_in[11]; ep.dst[3] = (const int*)d_in[12];  // ss

    // workspace (bytes), ~56.9 MB total; y aliases the dead cnt buffers
    // (k_ygemm runs after k_fill3, the last cnt2in reader).
    char* ws = (char*)d_ws;
    unsigned short* cnt2in = (unsigned short*)(ws + 0);        // [4][16][NB]
    unsigned short* cnt2o  = (unsigned short*)(ws + 6400000);  // [4][16][NB]
    _Float16* y    = (_Float16*)(ws + 0);                      // [4][NB][D] (51.2 MB)
    unsigned short* esrc = (unsigned short*)(ws + 51200000);   // [4][EB] u16 (4 MB)
    float* coef    = (float*)(ws + 55200000);   // [4][NB]
    int*   offs    = (int*)(ws + 56000000);     // [4][NB+1]
    int*   chunksum = (int*)(ws + 56800064);    // [4][NCH]
    _Float16* Wb   = (_Float16*)(ws + 56801664); // 128 KB packed W

    k_hist<<<dim3(NCHK, NRG, 8), 256, 0, stream>>>(ep, cnt2in, cnt2o);
    k_wpack<<<32, 256, 0, stream>>>(W, Wb);
    k_scan1<<<dim3(NCH, 4), 512, 0, stream>>>(cnt2in, cnt2o, coef, offs, chunksum);
    k_scan2<<<1, 256, 0, stream>>>(chunksum);
    k_scan3<<<dim3(NCH, 4), 512, 0, stream>>>(offs, chunksum);
    k_fill3<<<dim3(NCHK, NRG, 4), 256, 0, stream>>>(ep, cnt2in, offs, esrc);
    k_ygemm<<<dim3(782, 4), 256, 0, stream>>>(x_drug, x_dis, Wb, coef, y);
    k_gather<<<dim3(NB / 16, 2), 256, 0, stream>>>(
        (const unsigned short*)y, offs, esrc, b, pa, (float*)d_out);
}

// Round 15
// 270.754 us; speedup vs baseline: 1.2484x; 1.2484x over previous
//
#include <hip/hip_runtime.h>
#include <hip/hip_fp16.h>

// Node_Embedding: HeteroGraphConv(sum) of 4 GraphConv relations + PReLU.
// Pipeline (no global atomics, no memsets):
//   k_cvt (x->fp16) ; k_hist (chunk x range LDS u16 histograms) ; k_scan1..3
//   (chunk-prefix + CSR offs + coef) ; k_fill3 (chunked LDS-cursor counting
//   sort, int2 (src,coef)) ; k_gather (src-range-BLOCKED gather: 64 rows &
//   one relation per block, 16 range passes w/ block barrier -> per-pass
//   working set 3.2MB fits 4MB XCD L2; per-row ballot-scan selects pass
//   edges) ; k_gemm (dense MFMA f16 GEMM + bias + PReLU).
// Model (R14): gather FETCH = per-XCD compulsory floor x (1-e^-lambda) term;
// deep blocks raise lambda, range passes keep the per-pass slab L2-resident.

#define NB 50000   // nodes per type
#define EB 500000  // edges per relation
#define D  128
#define NCH 98     // ceil(NB/512)
#define CAP 1024   // gather LDS edge capacity (mean 640 per 64 rows)
#define NCHK 16    // edge chunks (CSR build)
#define CH2 15625  // (EB/NCHK)/2 int2 loads per chunk
#define NRG 8      // node ranges (CSR build)
#define FR 6250    // nodes per range (CSR build)
#define NRGP 16    // gather src-range passes (3125 nodes each)
#define RQ 3125    // NB/NRGP

struct EdgePtrs { const int* src[4]; const int* dst[4]; };

typedef _Float16 f16x8 __attribute__((ext_vector_type(8)));
typedef float f32x4 __attribute__((ext_vector_type(4)));

__device__ inline float hlo(unsigned u) {
    return __half2float(__ushort_as_half((unsigned short)(u & 0xffffu)));
}
__device__ inline float hhi(unsigned u) {
    return __half2float(__ushort_as_half((unsigned short)(u >> 16)));
}

// x (fp32) -> fp16, float4/thread.
__global__ __launch_bounds__(256) void k_cvt(const float* __restrict__ xd,
                                             const float* __restrict__ xs,
                                             unsigned short* __restrict__ xh) {
    int i = blockIdx.x * 256 + threadIdx.x;   // float4 index, 3.2M total
    const int half = NB * D / 4;
    const float* src = (i < half) ? xd : xs;
    int j = (i < half) ? i : i - half;
    float4 v = reinterpret_cast<const float4*>(src)[j];
    ushort4 o;
    o.x = __half_as_ushort(__float2half(v.x));
    o.y = __half_as_ushort(__float2half(v.y));
    o.z = __half_as_ushort(__float2half(v.z));
    o.w = __half_as_ushort(__float2half(v.w));
    reinterpret_cast<ushort4*>(xh)[i] = o;
}

// Chunked LDS histogram. Block (chunk, range, z) with z = io*4 + rel.
__global__ __launch_bounds__(256) void k_hist(EdgePtrs ep,
                                              unsigned short* __restrict__ cnt2in,
                                              unsigned short* __restrict__ cnt2o) {
    __shared__ unsigned pk[FR / 2];   // packed u16 pairs, 12.5 KB
    const int chunk = blockIdx.x, range = blockIdx.y;
    const int rel = blockIdx.z & 3, io = blockIdx.z >> 2;
    const int lo = range * FR;
    const int* arr = io ? ep.src[rel] : ep.dst[rel];
    for (int i = threadIdx.x; i < FR / 2; i += 256) pk[i] = 0;
    __syncthreads();
    const int2* a2 = reinterpret_cast<const int2*>(arr) + (size_t)chunk * CH2;
    for (int i = threadIdx.x; i < CH2; i += 256) {
        int2 v = a2[i];
        int n0 = v.x - lo;
        if ((unsigned)n0 < (unsigned)FR) atomicAdd(&pk[n0 >> 1], 1u << (16 * (n0 & 1)));
        int n1 = v.y - lo;
        if ((unsigned)n1 < (unsigned)FR) atomicAdd(&pk[n1 >> 1], 1u << (16 * (n1 & 1)));
    }
    __syncthreads();
    unsigned short* out = io ? cnt2o : cnt2in;
    unsigned* dst = reinterpret_cast<unsigned*>(out + ((size_t)(rel * NCHK + chunk)) * NB);
    for (int i = threadIdx.x; i < FR / 2; i += 256) dst[lo / 2 + i] = pk[i];
}

// Pack W (fp32 [4][128][128]) into MFMA B-fragment order for Wcat_t, fp16.
__global__ __launch_bounds__(256) void k_wpack(const float* __restrict__ W,
                                               _Float16* __restrict__ Wb) {
    int idx = blockIdx.x * 256 + threadIdx.x;   // 8192 total
    int t = idx >> 12, jt = (idx >> 9) & 7, ks = (idx >> 6) & 7, l = idx & 63;
    int col = jt * 16 + (l & 15);
    int kb = ks * 32 + (l >> 4) * 8;
    _Float16 h[8];
#pragma unroll
    for (int m = 0; m < 8; ++m) {
        int k = kb + m;
        int r = (k < 128) ? t : (2 + t);
        h[m] = (_Float16)W[r * D * D + (k & 127) * D + col];
    }
    *reinterpret_cast<f16x8*>(Wb + (size_t)idx * 8) = *reinterpret_cast<f16x8*>(h);
}

// Phase 1: per node — chunk-prefix cnt2in in place (u16), outdeg -> coef,
// then per-512-node exclusive block scan of total in-degree.
__global__ __launch_bounds__(512) void k_scan1(unsigned short* __restrict__ cnt2in,
                                               const unsigned short* __restrict__ cnt2o,
                                               float* __restrict__ coef,
                                               int* __restrict__ offs,
                                               int* __restrict__ chunksum) {
    int r = blockIdx.y, c = blockIdx.x, t = threadIdx.x;
    int node = c * 512 + t;
    int v = 0;
    if (node < NB) {
        int tin = 0;
#pragma unroll
        for (int k = 0; k < NCHK; ++k) {
            size_t idx = ((size_t)(r * NCHK + k)) * NB + node;
            int cc = cnt2in[idx];
            cnt2in[idx] = (unsigned short)tin;   // exclusive chunk prefix
            tin += cc;
        }
        v = tin;
        int tout = 0;
#pragma unroll
        for (int k = 0; k < NCHK; ++k)
            tout += cnt2o[((size_t)(r * NCHK + k)) * NB + node];
        coef[r * NB + node] = rsqrtf((float)(tout > 1 ? tout : 1));
    }
    __shared__ int sh[512];
    sh[t] = v;
    __syncthreads();
    for (int off = 1; off < 512; off <<= 1) {
        int u = (t >= off) ? sh[t - off] : 0;
        __syncthreads();
        sh[t] += u;
        __syncthreads();
    }
    int incl = sh[t];
    if (node < NB) offs[r * (NB + 1) + node] = incl - v;  // local exclusive
    if (t == 511) chunksum[r * NCH + c] = incl;
}

// Phase 2: exclusive scan of the NCH chunk totals per relation (wave r).
__global__ __launch_bounds__(256) void k_scan2(int* __restrict__ chunksum) {
    int r = threadIdx.x >> 6, lane = threadIdx.x & 63;
    int* cs = chunksum + r * NCH;
    int s0 = cs[lane];
    int s1 = (64 + lane < NCH) ? cs[64 + lane] : 0;
    int x = s0;
    for (int d = 1; d < 64; d <<= 1) { int u = __shfl_up(x, d, 64); if (lane >= d) x += u; }
    int tot0 = __shfl(x, 63, 64);
    int y = s1;
    for (int d = 1; d < 64; d <<= 1) { int u = __shfl_up(y, d, 64); if (lane >= d) y += u; }
    y += tot0;
    cs[lane] = x - s0;
    if (64 + lane < NCH) cs[64 + lane] = y - s1;
}

// Phase 3: add chunk base; offs[NB] = EB.
__global__ __launch_bounds__(512) void k_scan3(int* __restrict__ offs,
                                               const int* __restrict__ chunksum) {
    int r = blockIdx.y, c = blockIdx.x, t = threadIdx.x;
    int node = c * 512 + t;
    if (node < NB)
        offs[r * (NB + 1) + node] += chunksum[r * NCH + c];
    if (c == NCH - 1 && t == 0) offs[r * (NB + 1) + NB] = EB;
}

// Chunked counting-sort placement: int2 (src, coef) payload.
__global__ __launch_bounds__(256) void k_fill3(EdgePtrs ep,
                                               const unsigned short* __restrict__ cnt2in,
                                               const float* __restrict__ coef,
                                               const int* __restrict__ offs,
                                               int2* __restrict__ epack) {
    __shared__ int cur[FR];           // 25 KB
    const int chunk = blockIdx.x, range = blockIdx.y, rel = blockIdx.z;
    const int lo = range * FR;
    const unsigned short* pre = cnt2in + ((size_t)(rel * NCHK + chunk)) * NB;
    for (int i = threadIdx.x; i < FR; i += 256)
        cur[i] = offs[rel * (NB + 1) + lo + i] + pre[lo + i];
    __syncthreads();
    const int2* d2p = reinterpret_cast<const int2*>(ep.dst[rel]) + (size_t)chunk * CH2;
    const int2* s2p = reinterpret_cast<const int2*>(ep.src[rel]) + (size_t)chunk * CH2;
    const float* cf = coef + rel * NB;
    int2* epk = epack + (size_t)rel * EB;
    for (int i = threadIdx.x; i < CH2; i += 256) {
        int2 d2 = d2p[i];
        int2 s2 = s2p[i];
        int n0 = d2.x - lo;
        if ((unsigned)n0 < (unsigned)FR) {
            int pos = atomicAdd(&cur[n0], 1);
            epk[pos] = make_int2(s2.x, __float_as_int(cf[s2.x]));
        }
        int n1 = d2.y - lo;
        if ((unsigned)n1 < (unsigned)FR) {
            int pos = atomicAdd(&cur[n1], 1);
            epk[pos] = make_int2(s2.y, __float_as_int(cf[s2.y]));
        }
    }
}

#define FMA8A(c, rv, A)                                                        \
    {                                                                          \
        A[0] = fmaf(hlo(rv.x), c, A[0]); A[1] = fmaf(hhi(rv.x), c, A[1]);      \
        A[2] = fmaf(hlo(rv.y), c, A[2]); A[3] = fmaf(hhi(rv.y), c, A[3]);      \
        A[4] = fmaf(hlo(rv.z), c, A[4]); A[5] = fmaf(hhi(rv.z), c, A[5]);      \
        A[6] = fmaf(hlo(rv.w), c, A[6]); A[7] = fmaf(hhi(rv.w), c, A[7]);      \
    }

// Src-range-blocked gather. Block = 64 dst rows x ONE relation.
// blockIdx.y in 0..3: t = y>>1, h = y&1, rel = h ? 2+t : t.
// 16 groups x 16 lanes; group owns 4 rows. 16 range passes (src/3125),
// block barrier per pass; per-pass working set (4 slabs x 0.8MB) fits L2.
__global__ __launch_bounds__(256, 6) void k_gather(
    const unsigned short* __restrict__ xh,  // [2][NB][D] fp16: drug then dis
    const int* __restrict__ offs, const int2* __restrict__ epack,
    unsigned short* __restrict__ agg) {     // [2*NB][256] fp16 (aliases d_out)
    __shared__ int2 ebuf[CAP];
    __shared__ unsigned char rbuf[CAP + 16];
    __shared__ int soff[65];
    const int t = blockIdx.y >> 1, h = blockIdx.y & 1;
    const int rel = h ? (2 + t) : t;
    const int row0 = blockIdx.x * 64;
    const int tid = threadIdx.x;
    const int g = tid >> 4, l16 = tid & 15;
    const int quad = (tid >> 4) & 3;        // group within wave
    const int cbase = l16 * 8;              // this lane's 8 fp16 columns
    const unsigned short* x = xh + (size_t)(rel >= 2 ? NB * D : 0);
    const int2* epk = epack + (size_t)rel * EB;

    if (tid < 65) {
        int idx = row0 + tid; if (idx > NB) idx = NB;
        soff[tid] = offs[rel * (NB + 1) + idx];
    }
    __syncthreads();

    // stage this block's edge window (first CAP) + per-edge range byte
    const int base = soff[0];
    {
        int tot = soff[64] - base; if (tot > CAP) tot = CAP;
        for (int i = tid; i < tot; i += 256) {
            int2 e = epk[base + i];
            ebuf[i] = e;
            rbuf[i] = (unsigned char)((unsigned)e.x / RQ);
        }
    }
    __syncthreads();

    // per-row segment bounds (regs, uniform within group)
    int glo[4], ghi0[4], ghi[4];
    float dinv[4];
#pragma unroll
    for (int rr = 0; rr < 4; ++rr) {
        glo[rr]  = soff[g * 4 + rr] - base;
        ghi0[rr] = soff[g * 4 + rr + 1] - base;
        ghi[rr]  = ghi0[rr] < CAP ? ghi0[rr] : CAP;
        int dg = ghi0[rr] - glo[rr];
        dinv[rr] = rsqrtf((float)(dg > 1 ? dg : 1));
    }

    float racc[4][8] = {};

    // ---- range passes ----
    for (int r = 0; r < NRGP; ++r) {
#pragma unroll
        for (int rr = 0; rr < 4; ++rr) {
            for (int bse = glo[rr]; bse < ghi[rr]; bse += 16) {
                int n = ghi[rr] - bse;
                bool p = (l16 < n) && (rbuf[bse + l16] == (unsigned char)r);
                unsigned m = (unsigned)(__ballot(p) >> (quad * 16)) & 0xffffu;
                while (m) {
                    int bit = __ffs(m) - 1; m &= m - 1;
                    int2 e = ebuf[bse + bit];
                    float c = __int_as_float(e.y);
                    uint4 rv = *reinterpret_cast<const uint4*>(
                        x + ((unsigned)e.x * D + cbase));
                    FMA8A(c, rv, racc[rr]);
                }
            }
        }
        __syncthreads();
    }

    // rare overflow tail (window beyond CAP) straight from global, unsorted
#pragma unroll
    for (int rr = 0; rr < 4; ++rr) {
        int st = glo[rr] > CAP ? glo[rr] : CAP;
        for (int i = st; i < ghi0[rr]; ++i) {
            int2 e = epk[base + i];
            float c = __int_as_float(e.y);
            uint4 rv = *reinterpret_cast<const uint4*>(
                x + ((unsigned)e.x * D + cbase));
            FMA8A(c, rv, racc[rr]);
        }
    }

    // scale + store fp16 half-rows (256B contiguous per row per block-half)
#pragma unroll
    for (int rr = 0; rr < 4; ++rr) {
        int row = row0 + g * 4 + rr;
        if (row < NB) {
            float di = dinv[rr];
            unsigned q[4];
#pragma unroll
            for (int k2 = 0; k2 < 4; ++k2) {
                unsigned lo2 = __half_as_ushort(__float2half(racc[rr][2 * k2] * di));
                unsigned hi2 = __half_as_ushort(__float2half(racc[rr][2 * k2 + 1] * di));
                q[k2] = lo2 | (hi2 << 16);
            }
            *reinterpret_cast<uint4*>(
                agg + ((size_t)(t * NB + row) * 256 + h * 128 + cbase)) =
                make_uint4(q[0], q[1], q[2], q[3]);
        }
    }
}

// Dense MFMA GEMM: out[r][j] = prelu(sum_k agg[r][k] * Wcat_t[k][j] + bias).
__global__ __launch_bounds__(256) void k_gemm(
    const _Float16* agg,                    // aliases out
    const _Float16* __restrict__ Wb,
    const float* __restrict__ b, const float* __restrict__ prelu_a,
    float* out) {
    const int t = blockIdx.y;
    const int tid = threadIdx.x, w = tid >> 6, l = tid & 63;
    const int rbase = t * NB + blockIdx.x * 64 + w * 16;
    const int rmax = t * NB + NB - 1;
    const int lk = (l >> 4) * 8;
    f32x4 acc[8] = {};
    const f16x8* wb = reinterpret_cast<const f16x8*>(Wb + (size_t)t * 32768);
    int ra = rbase + (l & 15); if (ra > rmax) ra = rmax;
    const _Float16* ap = agg + (size_t)ra * 256 + lk;
#pragma unroll
    for (int ks = 0; ks < 8; ++ks) {
        f16x8 a = *reinterpret_cast<const f16x8*>(ap + ks * 32);
#pragma unroll
        for (int jt = 0; jt < 8; ++jt) {
            f16x8 bf = wb[(jt * 8 + ks) * 64 + l];
            acc[jt] = __builtin_amdgcn_mfma_f32_16x16x32_f16(a, bf, acc[jt], 0, 0, 0);
        }
    }
    float pa = prelu_a[0];
    const int rowoff = (l >> 4) * 4;
#pragma unroll
    for (int jt = 0; jt < 8; ++jt) {
        int col = jt * 16 + (l & 15);
        float bs = b[t * D + col] + b[(2 + t) * D + col];
#pragma unroll
        for (int m = 0; m < 4; ++m) {
            int grow = rbase + rowoff + m;
            if (grow <= rmax) {
                float v = acc[jt][m] + bs;
                v = v >= 0.f ? v : pa * v;
                out[(size_t)grow * D + col] = v;
            }
        }
    }
}

extern "C" void kernel_launch(void* const* d_in, const int* in_sizes, int n_in,
                              void* d_out, int out_size, void* d_ws, size_t ws_size,
                              hipStream_t stream) {
    const float* x_drug = (const float*)d_in[0];
    const float* x_dis  = (const float*)d_in[1];
    const float* W      = (const float*)d_in[2];   // [4,128,128]
    const float* b      = (const float*)d_in[3];   // [4,128]
    const float* pa     = (const float*)d_in[4];   // [1]
    EdgePtrs ep;
    ep.src[0] = (const int*)d_in[5];  ep.dst[0] = (const int*)d_in[6];   // dd
    ep.src[1] = (const int*)d_in[7];  ep.dst[1] = (const int*)d_in[8];   // ds
    ep.src[2] = (const int*)d_in[9];  ep.dst[2] = (const int*)d_in[10];  // sd
    ep.src[3] = (const int*)d_in[11]; ep.dst[3] = (const int*)d_in[12];  // ss

    // workspace layout (bytes); no memset needed — all buffers fully written
    char* ws = (char*)d_ws;
    unsigned short* cnt2in = (unsigned short*)(ws + 0);         // [4][16][NB]
    unsigned short* cnt2o  = (unsigned short*)(ws + 6400000);   // [4][16][NB]
    float* coef     = (float*)(ws + 12800000);  // [4][NB]
    int*   offs     = (int*)(ws + 13600000);    // [4][NB+1]
    int*   chunksum = (int*)(ws + 14400064);    // [4][NCH]
    int2*  epack    = (int2*)(ws + 14401664);   // [4][EB] int2 (16 MB)
    unsigned short* xh = (unsigned short*)(ws + 30401664);  // fp16 x (25.6 MB)
    _Float16* Wb    = (_Float16*)(ws + 56001664); // 128 KB packed W
    // total ~56.1 MB

    k_cvt<<<12500, 256, 0, stream>>>(x_drug, x_dis, xh);
    k_hist<<<dim3(NCHK, NRG, 8), 256, 0, stream>>>(ep, cnt2in, cnt2o);
    k_wpack<<<32, 256, 0, stream>>>(W, Wb);
    k_scan1<<<dim3(NCH, 4), 512, 0, stream>>>(cnt2in, cnt2o, coef, offs, chunksum);
    k_scan2<<<1, 256, 0, stream>>>(chunksum);
    k_scan3<<<dim3(NCH, 4), 512, 0, stream>>>(offs, chunksum);
    k_fill3<<<dim3(NCHK, NRG, 4), 256, 0, stream>>>(ep, cnt2in, coef, offs, epack);
    k_gather<<<dim3(782, 4), 256, 0, stream>>>(
        xh, offs, epack, (unsigned short*)d_out);
    k_gemm<<<dim3(782, 2), 256, 0, stream>>>(
        (const _Float16*)d_out, Wb, b, pa, (float*)d_out);
}

// Round 16
// 259.702 us; speedup vs baseline: 1.3015x; 1.0426x over previous
//
#include <hip/hip_runtime.h>
#include <hip/hip_fp16.h>

// Node_Embedding: HeteroGraphConv(sum) of 4 GraphConv relations + PReLU.
// Pipeline (no global atomics, no memsets):
//   k_cvt (x->fp16) ; k_hist (chunk x range LDS u16 histograms) ; k_scan1..3
//   (chunk-prefix + CSR offs + coef) ; k_fill3 (chunked LDS-cursor counting
//   sort, int2 (src,coef)) ; k_gather (src-range-blocked gather, edges
//   in-block SORTED by (row, src-range) -> direct run iteration, 16 range
//   passes w/ block barrier keep per-pass slab L2-resident) ; k_gemm (MFMA).
// R15 validated: range-blocking cut FETCH 372->147MB and killed the write
// amplification (475->50MB). Gather is now VALU/latency-bound -> this round
// removes the ballot-scan overhead (sorted runs) and raises occupancy to 8.

#define NB 50000   // nodes per type
#define EB 500000  // edges per relation
#define D  128
#define NCH 98     // ceil(NB/512)
#define CAP 1024   // gather LDS edge capacity (mean 640 per 64 rows)
#define NCHK 16    // edge chunks (CSR build)
#define CH2 15625  // (EB/NCHK)/2 int2 loads per chunk
#define NRG 4      // node ranges (CSR build)
#define FR 12500   // nodes per range (CSR build)
#define NRGP 16    // gather src-range passes
#define RQ 3125    // NB/NRGP

struct EdgePtrs { const int* src[4]; const int* dst[4]; };

typedef _Float16 f16x8 __attribute__((ext_vector_type(8)));
typedef float f32x4 __attribute__((ext_vector_type(4)));

__device__ inline float hlo(unsigned u) {
    return __half2float(__ushort_as_half((unsigned short)(u & 0xffffu)));
}
__device__ inline float hhi(unsigned u) {
    return __half2float(__ushort_as_half((unsigned short)(u >> 16)));
}

// x (fp32) -> fp16, float4/thread.
__global__ __launch_bounds__(256) void k_cvt(const float* __restrict__ xd,
                                             const float* __restrict__ xs,
                                             unsigned short* __restrict__ xh) {
    int i = blockIdx.x * 256 + threadIdx.x;   // float4 index, 3.2M total
    const int half = NB * D / 4;
    const float* src = (i < half) ? xd : xs;
    int j = (i < half) ? i : i - half;
    float4 v = reinterpret_cast<const float4*>(src)[j];
    ushort4 o;
    o.x = __half_as_ushort(__float2half(v.x));
    o.y = __half_as_ushort(__float2half(v.y));
    o.z = __half_as_ushort(__float2half(v.z));
    o.w = __half_as_ushort(__float2half(v.w));
    reinterpret_cast<ushort4*>(xh)[i] = o;
}

// Chunked LDS histogram. Block (chunk, range, z) with z = io*4 + rel.
__global__ __launch_bounds__(256) void k_hist(EdgePtrs ep,
                                              unsigned short* __restrict__ cnt2in,
                                              unsigned short* __restrict__ cnt2o) {
    __shared__ unsigned pk[FR / 2];   // packed u16 pairs, 25 KB
    const int chunk = blockIdx.x, range = blockIdx.y;
    const int rel = blockIdx.z & 3, io = blockIdx.z >> 2;
    const int lo = range * FR;
    const int* arr = io ? ep.src[rel] : ep.dst[rel];
    for (int i = threadIdx.x; i < FR / 2; i += 256) pk[i] = 0;
    __syncthreads();
    const int2* a2 = reinterpret_cast<const int2*>(arr) + (size_t)chunk * CH2;
    for (int i = threadIdx.x; i < CH2; i += 256) {
        int2 v = a2[i];
        int n0 = v.x - lo;
        if ((unsigned)n0 < (unsigned)FR) atomicAdd(&pk[n0 >> 1], 1u << (16 * (n0 & 1)));
        int n1 = v.y - lo;
        if ((unsigned)n1 < (unsigned)FR) atomicAdd(&pk[n1 >> 1], 1u << (16 * (n1 & 1)));
    }
    __syncthreads();
    unsigned short* out = io ? cnt2o : cnt2in;
    unsigned* dst = reinterpret_cast<unsigned*>(out + ((size_t)(rel * NCHK + chunk)) * NB);
    for (int i = threadIdx.x; i < FR / 2; i += 256) dst[lo / 2 + i] = pk[i];
}

// Pack W (fp32 [4][128][128]) into MFMA B-fragment order for Wcat_t, fp16.
__global__ __launch_bounds__(256) void k_wpack(const float* __restrict__ W,
                                               _Float16* __restrict__ Wb) {
    int idx = blockIdx.x * 256 + threadIdx.x;   // 8192 total
    int t = idx >> 12, jt = (idx >> 9) & 7, ks = (idx >> 6) & 7, l = idx & 63;
    int col = jt * 16 + (l & 15);
    int kb = ks * 32 + (l >> 4) * 8;
    _Float16 h[8];
#pragma unroll
    for (int m = 0; m < 8; ++m) {
        int k = kb + m;
        int r = (k < 128) ? t : (2 + t);
        h[m] = (_Float16)W[r * D * D + (k & 127) * D + col];
    }
    *reinterpret_cast<f16x8*>(Wb + (size_t)idx * 8) = *reinterpret_cast<f16x8*>(h);
}

// Phase 1: per node — chunk-prefix cnt2in in place (u16), outdeg -> coef,
// then per-512-node exclusive block scan of total in-degree.
__global__ __launch_bounds__(512) void k_scan1(unsigned short* __restrict__ cnt2in,
                                               const unsigned short* __restrict__ cnt2o,
                                               float* __restrict__ coef,
                                               int* __restrict__ offs,
                                               int* __restrict__ chunksum) {
    int r = blockIdx.y, c = blockIdx.x, t = threadIdx.x;
    int node = c * 512 + t;
    int v = 0;
    if (node < NB) {
        int tin = 0;
#pragma unroll
        for (int k = 0; k < NCHK; ++k) {
            size_t idx = ((size_t)(r * NCHK + k)) * NB + node;
            int cc = cnt2in[idx];
            cnt2in[idx] = (unsigned short)tin;   // exclusive chunk prefix
            tin += cc;
        }
        v = tin;
        int tout = 0;
#pragma unroll
        for (int k = 0; k < NCHK; ++k)
            tout += cnt2o[((size_t)(r * NCHK + k)) * NB + node];
        coef[r * NB + node] = rsqrtf((float)(tout > 1 ? tout : 1));
    }
    __shared__ int sh[512];
    sh[t] = v;
    __syncthreads();
    for (int off = 1; off < 512; off <<= 1) {
        int u = (t >= off) ? sh[t - off] : 0;
        __syncthreads();
        sh[t] += u;
        __syncthreads();
    }
    int incl = sh[t];
    if (node < NB) offs[r * (NB + 1) + node] = incl - v;  // local exclusive
    if (t == 511) chunksum[r * NCH + c] = incl;
}

// Phase 2: exclusive scan of the NCH chunk totals per relation (wave r).
__global__ __launch_bounds__(256) void k_scan2(int* __restrict__ chunksum) {
    int r = threadIdx.x >> 6, lane = threadIdx.x & 63;
    int* cs = chunksum + r * NCH;
    int s0 = cs[lane];
    int s1 = (64 + lane < NCH) ? cs[64 + lane] : 0;
    int x = s0;
    for (int d = 1; d < 64; d <<= 1) { int u = __shfl_up(x, d, 64); if (lane >= d) x += u; }
    int tot0 = __shfl(x, 63, 64);
    int y = s1;
    for (int d = 1; d < 64; d <<= 1) { int u = __shfl_up(y, d, 64); if (lane >= d) y += u; }
    y += tot0;
    cs[lane] = x - s0;
    if (64 + lane < NCH) cs[64 + lane] = y - s1;
}

// Phase 3: add chunk base; offs[NB] = EB.
__global__ __launch_bounds__(512) void k_scan3(int* __restrict__ offs,
                                               const int* __restrict__ chunksum) {
    int r = blockIdx.y, c = blockIdx.x, t = threadIdx.x;
    int node = c * 512 + t;
    if (node < NB)
        offs[r * (NB + 1) + node] += chunksum[r * NCH + c];
    if (c == NCH - 1 && t == 0) offs[r * (NB + 1) + NB] = EB;
}

// Chunked counting-sort placement: int2 (src, coef) payload.
__global__ __launch_bounds__(256) void k_fill3(EdgePtrs ep,
                                               const unsigned short* __restrict__ cnt2in,
                                               const float* __restrict__ coef,
                                               const int* __restrict__ offs,
                                               int2* __restrict__ epack) {
    __shared__ int cur[FR];           // 50 KB
    const int chunk = blockIdx.x, range = blockIdx.y, rel = blockIdx.z;
    const int lo = range * FR;
    const unsigned short* pre = cnt2in + ((size_t)(rel * NCHK + chunk)) * NB;
    for (int i = threadIdx.x; i < FR; i += 256)
        cur[i] = offs[rel * (NB + 1) + lo + i] + pre[lo + i];
    __syncthreads();
    const int2* d2p = reinterpret_cast<const int2*>(ep.dst[rel]) + (size_t)chunk * CH2;
    const int2* s2p = reinterpret_cast<const int2*>(ep.src[rel]) + (size_t)chunk * CH2;
    const float* cf = coef + rel * NB;
    int2* epk = epack + (size_t)rel * EB;
    for (int i = threadIdx.x; i < CH2; i += 256) {
        int2 d2 = d2p[i];
        int2 s2 = s2p[i];
        int n0 = d2.x - lo;
        if ((unsigned)n0 < (unsigned)FR) {
            int pos = atomicAdd(&cur[n0], 1);
            epk[pos] = make_int2(s2.x, __float_as_int(cf[s2.x]));
        }
        int n1 = d2.y - lo;
        if ((unsigned)n1 < (unsigned)FR) {
            int pos = atomicAdd(&cur[n1], 1);
            epk[pos] = make_int2(s2.y, __float_as_int(cf[s2.y]));
        }
    }
}

#define FMA8A(c, rv, A)                                                        \
    {                                                                          \
        A[0] = fmaf(hlo(rv.x), c, A[0]); A[1] = fmaf(hhi(rv.x), c, A[1]);      \
        A[2] = fmaf(hlo(rv.y), c, A[2]); A[3] = fmaf(hhi(rv.y), c, A[3]);      \
        A[4] = fmaf(hlo(rv.z), c, A[4]); A[5] = fmaf(hhi(rv.z), c, A[5]);      \
        A[6] = fmaf(hlo(rv.w), c, A[6]); A[7] = fmaf(hhi(rv.w), c, A[7]);      \
    }

// Src-range-blocked gather, edges in-block sorted by (row, range).
// Block = 64 dst rows x ONE relation (blockIdx.y: t = y>>1, h = y&1).
// Staging: count (row,range) -> per-row run table -> scatter sorted.
// Pass loop: direct iteration over each row's range-r run, barrier per pass.
__global__ __launch_bounds__(256, 8) void k_gather(
    const unsigned short* __restrict__ xh,  // [2][NB][D] fp16: drug then dis
    const int* __restrict__ offs, const int2* __restrict__ epack,
    unsigned short* __restrict__ agg) {     // [2*NB][256] fp16 (aliases d_out)
    __shared__ int2 ebuf[CAP];              // 8 KB (sorted)
    __shared__ unsigned short key[CAP];     // 2 KB (row*16+range per edge)
    __shared__ int soff[65];
    __shared__ int cnt[64 * 16];            // 4 KB: counts -> scatter cursors
    __shared__ int runstart[64 * 17];       // 4.25 KB: run boundaries
    const int t = blockIdx.y >> 1, h = blockIdx.y & 1;
    const int rel = h ? (2 + t) : t;
    const int row0 = blockIdx.x * 64;
    const int tid = threadIdx.x;
    const int g = tid >> 4, l16 = tid & 15;
    const int cbase = l16 * 8;              // this lane's 8 fp16 columns
    const unsigned short* x = xh + (size_t)(rel >= 2 ? NB * D : 0);
    const int2* epk = epack + (size_t)rel * EB;

    if (tid < 65) {
        int idx = row0 + tid; if (idx > NB) idx = NB;
        soff[tid] = offs[rel * (NB + 1) + idx];
    }
    for (int i = tid; i < 64 * 16; i += 256) cnt[i] = 0;
    __syncthreads();

    const int base = soff[0];
    const int tot0 = soff[64] - base;
    const int tot = tot0 < CAP ? tot0 : CAP;

    // pass A: count (row, range); row via binary search over soff
    for (int i = tid; i < tot; i += 256) {
        int2 e = epk[base + i];
        int rng = (int)((unsigned)e.x / RQ);
        int lo = 0, hi = 64;
        while (hi - lo > 1) {
            int mid = (lo + hi) >> 1;
            if (soff[mid] - base <= i) lo = mid; else hi = mid;
        }
        int k = lo * 16 + rng;
        key[i] = (unsigned short)k;
        atomicAdd(&cnt[k], 1);
    }
    __syncthreads();

    // per-row exclusive prefix over ranges -> run table + scatter cursors
    if (tid < 64) {
        int run = soff[tid] - base; if (run > CAP) run = CAP;
        for (int r = 0; r < 16; ++r) {
            int c = cnt[tid * 16 + r];
            runstart[tid * 17 + r] = run;
            cnt[tid * 16 + r] = run;
            run += c;
        }
        runstart[tid * 17 + 16] = run;
    }
    __syncthreads();

    // pass B: scatter into sorted order (re-read epk; L2-hot)
    for (int i = tid; i < tot; i += 256) {
        int2 e = epk[base + i];
        int pos = atomicAdd(&cnt[key[i]], 1);
        ebuf[pos] = e;
    }
    __syncthreads();

    // per-row segment bounds (group-uniform)
    int glo[4], ghi0[4];
    float dinv[4];
#pragma unroll
    for (int rr = 0; rr < 4; ++rr) {
        glo[rr]  = soff[g * 4 + rr] - base;
        ghi0[rr] = soff[g * 4 + rr + 1] - base;
        int dg = ghi0[rr] - glo[rr];
        dinv[rr] = rsqrtf((float)(dg > 1 ? dg : 1));
    }

    float racc[4][8] = {};

    // ---- range passes: direct run iteration ----
    for (int r = 0; r < NRGP; ++r) {
#pragma unroll
        for (int rr = 0; rr < 4; ++rr) {
            int row = g * 4 + rr;
            int s = runstart[row * 17 + r], e_ = runstart[row * 17 + r + 1];
            for (int i = s; i < e_; ++i) {
                int2 e = ebuf[i];
                float c = __int_as_float(e.y);
                uint4 rv = *reinterpret_cast<const uint4*>(
                    x + ((unsigned)e.x * D + cbase));
                FMA8A(c, rv, racc[rr]);
            }
        }
        __syncthreads();
    }

    // rare overflow tail (window beyond CAP) straight from global, unsorted
#pragma unroll
    for (int rr = 0; rr < 4; ++rr) {
        int st = glo[rr] > CAP ? glo[rr] : CAP;
        for (int i = st; i < ghi0[rr]; ++i) {
            int2 e = epk[base + i];
            float c = __int_as_float(e.y);
            uint4 rv = *reinterpret_cast<const uint4*>(
                x + ((unsigned)e.x * D + cbase));
            FMA8A(c, rv, racc[rr]);
        }
    }

    // scale + store fp16 half-rows (256B contiguous per row per block-half)
#pragma unroll
    for (int rr = 0; rr < 4; ++rr) {
        int row = row0 + g * 4 + rr;
        if (row < NB) {
            float di = dinv[rr];
            unsigned q[4];
#pragma unroll
            for (int k2 = 0; k2 < 4; ++k2) {
                unsigned lo2 = __half_as_ushort(__float2half(racc[rr][2 * k2] * di));
                unsigned hi2 = __half_as_ushort(__float2half(racc[rr][2 * k2 + 1] * di));
                q[k2] = lo2 | (hi2 << 16);
            }
            *reinterpret_cast<uint4*>(
                agg + ((size_t)(t * NB + row) * 256 + h * 128 + cbase)) =
                make_uint4(q[0], q[1], q[2], q[3]);
        }
    }
}

// Dense MFMA GEMM: out[r][j] = prelu(sum_k agg[r][k] * Wcat_t[k][j] + bias).
__global__ __launch_bounds__(256) void k_gemm(
    const _Float16* agg,                    // aliases out
    const _Float16* __restrict__ Wb,
    const float* __restrict__ b, const float* __restrict__ prelu_a,
    float* out) {
    const int t = blockIdx.y;
    const int tid = threadIdx.x, w = tid >> 6, l = tid & 63;
    const int rbase = t * NB + blockIdx.x * 64 + w * 16;
    const int rmax = t * NB + NB - 1;
    const int lk = (l >> 4) * 8;
    f32x4 acc[8] = {};
    const f16x8* wb = reinterpret_cast<const f16x8*>(Wb + (size_t)t * 32768);
    int ra = rbase + (l & 15); if (ra > rmax) ra = rmax;
    const _Float16* ap = agg + (size_t)ra * 256 + lk;
#pragma unroll
    for (int ks = 0; ks < 8; ++ks) {
        f16x8 a = *reinterpret_cast<const f16x8*>(ap + ks * 32);
#pragma unroll
        for (int jt = 0; jt < 8; ++jt) {
            f16x8 bf = wb[(jt * 8 + ks) * 64 + l];
            acc[jt] = __builtin_amdgcn_mfma_f32_16x16x32_f16(a, bf, acc[jt], 0, 0, 0);
        }
    }
    float pa = prelu_a[0];
    const int rowoff = (l >> 4) * 4;
#pragma unroll
    for (int jt = 0; jt < 8; ++jt) {
        int col = jt * 16 + (l & 15);
        float bs = b[t * D + col] + b[(2 + t) * D + col];
#pragma unroll
        for (int m = 0; m < 4; ++m) {
            int grow = rbase + rowoff + m;
            if (grow <= rmax) {
                float v = acc[jt][m] + bs;
                v = v >= 0.f ? v : pa * v;
                out[(size_t)grow * D + col] = v;
            }
        }
    }
}

extern "C" void kernel_launch(void* const* d_in, const int* in_sizes, int n_in,
                              void* d_out, int out_size, void* d_ws, size_t ws_size,
                              hipStream_t stream) {
    const float* x_drug = (const float*)d_in[0];
    const float* x_dis  = (const float*)d_in[1];
    const float* W      = (const float*)d_in[2];   // [4,128,128]
    const float* b      = (const float*)d_in[3];   // [4,128]
    const float* pa     = (const float*)d_in[4];   // [1]
    EdgePtrs ep;
    ep.src[0] = (const int*)d_in[5];  ep.dst[0] = (const int*)d_in[6];   // dd
    ep.src[1] = (const int*)d_in[7];  ep.dst[1] = (const int*)d_in[8];   // ds
    ep.src[2] = (const int*)d_in[9];  ep.dst[2] = (const int*)d_in[10];  // sd
    ep.src[3] = (const int*)d_in[11]; ep.dst[3] = (const int*)d_in[12];  // ss

    // workspace layout (bytes); no memset needed — all buffers fully written
    char* ws = (char*)d_ws;
    unsigned short* cnt2in = (unsigned short*)(ws + 0);         // [4][16][NB]
    unsigned short* cnt2o  = (unsigned short*)(ws + 6400000);   // [4][16][NB]
    float* coef     = (float*)(ws + 12800000);  // [4][NB]
    int*   offs     = (int*)(ws + 13600000);    // [4][NB+1]
    int*   chunksum = (int*)(ws + 14400064);    // [4][NCH]
    int2*  epack    = (int2*)(ws + 14401664);   // [4][EB] int2 (16 MB)
    unsigned short* xh = (unsigned short*)(ws + 30401664);  // fp16 x (25.6 MB)
    _Float16* Wb    = (_Float16*)(ws + 56001664); // 128 KB packed W
    // total ~56.1 MB

    k_cvt<<<12500, 256, 0, stream>>>(x_drug, x_dis, xh);
    k_hist<<<dim3(NCHK, NRG, 8), 256, 0, stream>>>(ep, cnt2in, cnt2o);
    k_wpack<<<32, 256, 0, stream>>>(W, Wb);
    k_scan1<<<dim3(NCH, 4), 512, 0, stream>>>(cnt2in, cnt2o, coef, offs, chunksum);
    k_scan2<<<1, 256, 0, stream>>>(chunksum);
    k_scan3<<<dim3(NCH, 4), 512, 0, stream>>>(offs, chunksum);
    k_fill3<<<dim3(NCHK, NRG, 4), 256, 0, stream>>>(ep, cnt2in, coef, offs, epack);
    k_gather<<<dim3(782, 4), 256, 0, stream>>>(
        xh, offs, epack, (unsigned short*)d_out);
    k_gemm<<<dim3(782, 2), 256, 0, stream>>>(
        (const _Float16*)d_out, Wb, b, pa, (float*)d_out);
}

// Round 17
// 235.240 us; speedup vs baseline: 1.4369x; 1.1040x over previous
//
#include <hip/hip_runtime.h>
#include <hip/hip_fp16.h>

// Node_Embedding: HeteroGraphConv(sum) of 4 GraphConv relations + PReLU.
// Pipeline (no global atomics, no memsets):
//   k_cvt (x->fp16 + W-pack) ; k_hist (chunk x range LDS u16 histograms) ;
//   k_scan1..3 (chunk-prefix + CSR offs + coef) ; k_fill3 (chunked LDS-cursor
//   counting sort, int2 (src,coef)) ; k_gather (src-range-blocked gather,
//   edges in-block sorted by (row, range) -> direct run iteration, 8 range
//   passes w/ block barrier keep per-pass slab L2-resident) ; k_gemm (MFMA).
// R15/R16 validated: range-blocking cut L2-miss traffic 372->147MB and
// killed write amplification; sorted runs cut scan overhead. This round
// halves the pass count (NRGP 16->8): barriers and run-lookups halve, runs
// lengthen; slab set 3.2MB still fits the 4MB per-XCD L2.

#define NB 50000   // nodes per type
#define EB 500000  // edges per relation
#define D  128
#define NCH 98     // ceil(NB/512)
#define CAP 1024   // gather LDS edge capacity (mean 640 per 64 rows)
#define NCHK 16    // edge chunks (CSR build)
#define CH2 15625  // (EB/NCHK)/2 int2 loads per chunk
#define NRG 4      // node ranges (CSR build)
#define FR 12500   // nodes per range (CSR build)
#define NRGP 8     // gather src-range passes
#define RQ 6250    // NB/NRGP

struct EdgePtrs { const int* src[4]; const int* dst[4]; };

typedef _Float16 f16x8 __attribute__((ext_vector_type(8)));
typedef float f32x4 __attribute__((ext_vector_type(4)));

__device__ inline float hlo(unsigned u) {
    return __half2float(__ushort_as_half((unsigned short)(u & 0xffffu)));
}
__device__ inline float hhi(unsigned u) {
    return __half2float(__ushort_as_half((unsigned short)(u >> 16)));
}

// x (fp32) -> fp16, float4/thread; last 32 blocks pack W into MFMA B-frags.
__global__ __launch_bounds__(256) void k_cvt(const float* __restrict__ xd,
                                             const float* __restrict__ xs,
                                             unsigned short* __restrict__ xh,
                                             const float* __restrict__ W,
                                             _Float16* __restrict__ Wb) {
    int bx = blockIdx.x;
    if (bx < 12500) {
        int i = bx * 256 + threadIdx.x;   // float4 index, 3.2M total
        const int half = NB * D / 4;
        const float* src = (i < half) ? xd : xs;
        int j = (i < half) ? i : i - half;
        float4 v = reinterpret_cast<const float4*>(src)[j];
        ushort4 o;
        o.x = __half_as_ushort(__float2half(v.x));
        o.y = __half_as_ushort(__float2half(v.y));
        o.z = __half_as_ushort(__float2half(v.z));
        o.w = __half_as_ushort(__float2half(v.w));
        reinterpret_cast<ushort4*>(xh)[i] = o;
    } else {
        int idx = (bx - 12500) * 256 + threadIdx.x;   // 8192 total
        int t = idx >> 12, jt = (idx >> 9) & 7, ks = (idx >> 6) & 7, l = idx & 63;
        int col = jt * 16 + (l & 15);
        int kb = ks * 32 + (l >> 4) * 8;
        _Float16 h[8];
#pragma unroll
        for (int m = 0; m < 8; ++m) {
            int k = kb + m;
            int r = (k < 128) ? t : (2 + t);
            h[m] = (_Float16)W[r * D * D + (k & 127) * D + col];
        }
        *reinterpret_cast<f16x8*>(Wb + (size_t)idx * 8) = *reinterpret_cast<f16x8*>(h);
    }
}

// Chunked LDS histogram. Block (chunk, range, z) with z = io*4 + rel.
__global__ __launch_bounds__(256) void k_hist(EdgePtrs ep,
                                              unsigned short* __restrict__ cnt2in,
                                              unsigned short* __restrict__ cnt2o) {
    __shared__ unsigned pk[FR / 2];   // packed u16 pairs, 25 KB
    const int chunk = blockIdx.x, range = blockIdx.y;
    const int rel = blockIdx.z & 3, io = blockIdx.z >> 2;
    const int lo = range * FR;
    const int* arr = io ? ep.src[rel] : ep.dst[rel];
    for (int i = threadIdx.x; i < FR / 2; i += 256) pk[i] = 0;
    __syncthreads();
    const int2* a2 = reinterpret_cast<const int2*>(arr) + (size_t)chunk * CH2;
    for (int i = threadIdx.x; i < CH2; i += 256) {
        int2 v = a2[i];
        int n0 = v.x - lo;
        if ((unsigned)n0 < (unsigned)FR) atomicAdd(&pk[n0 >> 1], 1u << (16 * (n0 & 1)));
        int n1 = v.y - lo;
        if ((unsigned)n1 < (unsigned)FR) atomicAdd(&pk[n1 >> 1], 1u << (16 * (n1 & 1)));
    }
    __syncthreads();
    unsigned short* out = io ? cnt2o : cnt2in;
    unsigned* dst = reinterpret_cast<unsigned*>(out + ((size_t)(rel * NCHK + chunk)) * NB);
    for (int i = threadIdx.x; i < FR / 2; i += 256) dst[lo / 2 + i] = pk[i];
}

// Phase 1: per node — chunk-prefix cnt2in in place (u16), outdeg -> coef,
// then per-512-node exclusive block scan of total in-degree.
__global__ __launch_bounds__(512) void k_scan1(unsigned short* __restrict__ cnt2in,
                                               const unsigned short* __restrict__ cnt2o,
                                               float* __restrict__ coef,
                                               int* __restrict__ offs,
                                               int* __restrict__ chunksum) {
    int r = blockIdx.y, c = blockIdx.x, t = threadIdx.x;
    int node = c * 512 + t;
    int v = 0;
    if (node < NB) {
        int tin = 0;
#pragma unroll
        for (int k = 0; k < NCHK; ++k) {
            size_t idx = ((size_t)(r * NCHK + k)) * NB + node;
            int cc = cnt2in[idx];
            cnt2in[idx] = (unsigned short)tin;   // exclusive chunk prefix
            tin += cc;
        }
        v = tin;
        int tout = 0;
#pragma unroll
        for (int k = 0; k < NCHK; ++k)
            tout += cnt2o[((size_t)(r * NCHK + k)) * NB + node];
        coef[r * NB + node] = rsqrtf((float)(tout > 1 ? tout : 1));
    }
    __shared__ int sh[512];
    sh[t] = v;
    __syncthreads();
    for (int off = 1; off < 512; off <<= 1) {
        int u = (t >= off) ? sh[t - off] : 0;
        __syncthreads();
        sh[t] += u;
        __syncthreads();
    }
    int incl = sh[t];
    if (node < NB) offs[r * (NB + 1) + node] = incl - v;  // local exclusive
    if (t == 511) chunksum[r * NCH + c] = incl;
}

// Phase 2: exclusive scan of the NCH chunk totals per relation (wave r).
__global__ __launch_bounds__(256) void k_scan2(int* __restrict__ chunksum) {
    int r = threadIdx.x >> 6, lane = threadIdx.x & 63;
    int* cs = chunksum + r * NCH;
    int s0 = cs[lane];
    int s1 = (64 + lane < NCH) ? cs[64 + lane] : 0;
    int x = s0;
    for (int d = 1; d < 64; d <<= 1) { int u = __shfl_up(x, d, 64); if (lane >= d) x += u; }
    int tot0 = __shfl(x, 63, 64);
    int y = s1;
    for (int d = 1; d < 64; d <<= 1) { int u = __shfl_up(y, d, 64); if (lane >= d) y += u; }
    y += tot0;
    cs[lane] = x - s0;
    if (64 + lane < NCH) cs[64 + lane] = y - s1;
}

// Phase 3: add chunk base; offs[NB] = EB.
__global__ __launch_bounds__(512) void k_scan3(int* __restrict__ offs,
                                               const int* __restrict__ chunksum) {
    int r = blockIdx.y, c = blockIdx.x, t = threadIdx.x;
    int node = c * 512 + t;
    if (node < NB)
        offs[r * (NB + 1) + node] += chunksum[r * NCH + c];
    if (c == NCH - 1 && t == 0) offs[r * (NB + 1) + NB] = EB;
}

// Chunked counting-sort placement: int2 (src, coef) payload.
__global__ __launch_bounds__(256) void k_fill3(EdgePtrs ep,
                                               const unsigned short* __restrict__ cnt2in,
                                               const float* __restrict__ coef,
                                               const int* __restrict__ offs,
                                               int2* __restrict__ epack) {
    __shared__ int cur[FR];           // 50 KB
    const int chunk = blockIdx.x, range = blockIdx.y, rel = blockIdx.z;
    const int lo = range * FR;
    const unsigned short* pre = cnt2in + ((size_t)(rel * NCHK + chunk)) * NB;
    for (int i = threadIdx.x; i < FR; i += 256)
        cur[i] = offs[rel * (NB + 1) + lo + i] + pre[lo + i];
    __syncthreads();
    const int2* d2p = reinterpret_cast<const int2*>(ep.dst[rel]) + (size_t)chunk * CH2;
    const int2* s2p = reinterpret_cast<const int2*>(ep.src[rel]) + (size_t)chunk * CH2;
    const float* cf = coef + rel * NB;
    int2* epk = epack + (size_t)rel * EB;
    for (int i = threadIdx.x; i < CH2; i += 256) {
        int2 d2 = d2p[i];
        int2 s2 = s2p[i];
        int n0 = d2.x - lo;
        if ((unsigned)n0 < (unsigned)FR) {
            int pos = atomicAdd(&cur[n0], 1);
            epk[pos] = make_int2(s2.x, __float_as_int(cf[s2.x]));
        }
        int n1 = d2.y - lo;
        if ((unsigned)n1 < (unsigned)FR) {
            int pos = atomicAdd(&cur[n1], 1);
            epk[pos] = make_int2(s2.y, __float_as_int(cf[s2.y]));
        }
    }
}

#define FMA8A(c, rv, A)                                                        \
    {                                                                          \
        A[0] = fmaf(hlo(rv.x), c, A[0]); A[1] = fmaf(hhi(rv.x), c, A[1]);      \
        A[2] = fmaf(hlo(rv.y), c, A[2]); A[3] = fmaf(hhi(rv.y), c, A[3]);      \
        A[4] = fmaf(hlo(rv.z), c, A[4]); A[5] = fmaf(hhi(rv.z), c, A[5]);      \
        A[6] = fmaf(hlo(rv.w), c, A[6]); A[7] = fmaf(hhi(rv.w), c, A[7]);      \
    }

// Src-range-blocked gather, edges in-block sorted by (row, range).
// Block = 64 dst rows x ONE relation (blockIdx.y: t = y>>1, h = y&1).
// Staging: count (row,range) -> per-row run table -> scatter sorted.
// Pass loop: direct iteration over each row's range-r run, barrier per pass.
__global__ __launch_bounds__(256, 8) void k_gather(
    const unsigned short* __restrict__ xh,  // [2][NB][D] fp16: drug then dis
    const int* __restrict__ offs, const int2* __restrict__ epack,
    unsigned short* __restrict__ agg) {     // [2*NB][256] fp16 (aliases d_out)
    __shared__ int2 ebuf[CAP];              // 8 KB (sorted)
    __shared__ unsigned short key[CAP];     // 2 KB (row*8+range per edge)
    __shared__ int soff[65];
    __shared__ int cnt[64 * NRGP];          // 2 KB: counts -> scatter cursors
    __shared__ int runstart[64 * (NRGP + 1)]; // 2.25 KB: run boundaries
    const int t = blockIdx.y >> 1, h = blockIdx.y & 1;
    const int rel = h ? (2 + t) : t;
    const int row0 = blockIdx.x * 64;
    const int tid = threadIdx.x;
    const int g = tid >> 4, l16 = tid & 15;
    const int cbase = l16 * 8;              // this lane's 8 fp16 columns
    const unsigned short* x = xh + (size_t)(rel >= 2 ? NB * D : 0);
    const int2* epk = epack + (size_t)rel * EB;

    if (tid < 65) {
        int idx = row0 + tid; if (idx > NB) idx = NB;
        soff[tid] = offs[rel * (NB + 1) + idx];
    }
    for (int i = tid; i < 64 * NRGP; i += 256) cnt[i] = 0;
    __syncthreads();

    const int base = soff[0];
    const int tot0 = soff[64] - base;
    const int tot = tot0 < CAP ? tot0 : CAP;

    // pass A: count (row, range); row via binary search over soff
    for (int i = tid; i < tot; i += 256) {
        int2 e = epk[base + i];
        int rng = (int)((unsigned)e.x / RQ);
        int lo = 0, hi = 64;
        while (hi - lo > 1) {
            int mid = (lo + hi) >> 1;
            if (soff[mid] - base <= i) lo = mid; else hi = mid;
        }
        int k = lo * NRGP + rng;
        key[i] = (unsigned short)k;
        atomicAdd(&cnt[k], 1);
    }
    __syncthreads();

    // per-row exclusive prefix over ranges -> run table + scatter cursors
    if (tid < 64) {
        int run = soff[tid] - base; if (run > CAP) run = CAP;
        for (int r = 0; r < NRGP; ++r) {
            int c = cnt[tid * NRGP + r];
            runstart[tid * (NRGP + 1) + r] = run;
            cnt[tid * NRGP + r] = run;
            run += c;
        }
        runstart[tid * (NRGP + 1) + NRGP] = run;
    }
    __syncthreads();

    // pass B: scatter into sorted order (re-read epk; L2-hot)
    for (int i = tid; i < tot; i += 256) {
        int2 e = epk[base + i];
        int pos = atomicAdd(&cnt[key[i]], 1);
        ebuf[pos] = e;
    }
    __syncthreads();

    // per-row segment bounds (group-uniform)
    int glo[4], ghi0[4];
    float dinv[4];
#pragma unroll
    for (int rr = 0; rr < 4; ++rr) {
        glo[rr]  = soff[g * 4 + rr] - base;
        ghi0[rr] = soff[g * 4 + rr + 1] - base;
        int dg = ghi0[rr] - glo[rr];
        dinv[rr] = rsqrtf((float)(dg > 1 ? dg : 1));
    }

    float racc[4][8] = {};

    // ---- range passes: direct run iteration ----
    for (int r = 0; r < NRGP; ++r) {
#pragma unroll
        for (int rr = 0; rr < 4; ++rr) {
            int row = g * 4 + rr;
            int s = runstart[row * (NRGP + 1) + r];
            int e_ = runstart[row * (NRGP + 1) + r + 1];
            for (int i = s; i < e_; ++i) {
                int2 e = ebuf[i];
                float c = __int_as_float(e.y);
                uint4 rv = *reinterpret_cast<const uint4*>(
                    x + ((unsigned)e.x * D + cbase));
                FMA8A(c, rv, racc[rr]);
            }
        }
        __syncthreads();
    }

    // rare overflow tail (window beyond CAP) straight from global, unsorted
#pragma unroll
    for (int rr = 0; rr < 4; ++rr) {
        int st = glo[rr] > CAP ? glo[rr] : CAP;
        for (int i = st; i < ghi0[rr]; ++i) {
            int2 e = epk[base + i];
            float c = __int_as_float(e.y);
            uint4 rv = *reinterpret_cast<const uint4*>(
                x + ((unsigned)e.x * D + cbase));
            FMA8A(c, rv, racc[rr]);
        }
    }

    // scale + store fp16 half-rows (256B contiguous per row per block-half)
#pragma unroll
    for (int rr = 0; rr < 4; ++rr) {
        int row = row0 + g * 4 + rr;
        if (row < NB) {
            float di = dinv[rr];
            unsigned q[4];
#pragma unroll
            for (int k2 = 0; k2 < 4; ++k2) {
                unsigned lo2 = __half_as_ushort(__float2half(racc[rr][2 * k2] * di));
                unsigned hi2 = __half_as_ushort(__float2half(racc[rr][2 * k2 + 1] * di));
                q[k2] = lo2 | (hi2 << 16);
            }
            *reinterpret_cast<uint4*>(
                agg + ((size_t)(t * NB + row) * 256 + h * 128 + cbase)) =
                make_uint4(q[0], q[1], q[2], q[3]);
        }
    }
}

// Dense MFMA GEMM: out[r][j] = prelu(sum_k agg[r][k] * Wcat_t[k][j] + bias).
__global__ __launch_bounds__(256) void k_gemm(
    const _Float16* agg,                    // aliases out
    const _Float16* __restrict__ Wb,
    const float* __restrict__ b, const float* __restrict__ prelu_a,
    float* out) {
    const int t = blockIdx.y;
    const int tid = threadIdx.x, w = tid >> 6, l = tid & 63;
    const int rbase = t * NB + blockIdx.x * 64 + w * 16;
    const int rmax = t * NB + NB - 1;
    const int lk = (l >> 4) * 8;
    f32x4 acc[8] = {};
    const f16x8* wb = reinterpret_cast<const f16x8*>(Wb + (size_t)t * 32768);
    int ra = rbase + (l & 15); if (ra > rmax) ra = rmax;
    const _Float16* ap = agg + (size_t)ra * 256 + lk;
#pragma unroll
    for (int ks = 0; ks < 8; ++ks) {
        f16x8 a = *reinterpret_cast<const f16x8*>(ap + ks * 32);
#pragma unroll
        for (int jt = 0; jt < 8; ++jt) {
            f16x8 bf = wb[(jt * 8 + ks) * 64 + l];
            acc[jt] = __builtin_amdgcn_mfma_f32_16x16x32_f16(a, bf, acc[jt], 0, 0, 0);
        }
    }
    float pa = prelu_a[0];
    const int rowoff = (l >> 4) * 4;
#pragma unroll
    for (int jt = 0; jt < 8; ++jt) {
        int col = jt * 16 + (l & 15);
        float bs = b[t * D + col] + b[(2 + t) * D + col];
#pragma unroll
        for (int m = 0; m < 4; ++m) {
            int grow = rbase + rowoff + m;
            if (grow <= rmax) {
                float v = acc[jt][m] + bs;
                v = v >= 0.f ? v : pa * v;
                out[(size_t)grow * D + col] = v;
            }
        }
    }
}

extern "C" void kernel_launch(void* const* d_in, const int* in_sizes, int n_in,
                              void* d_out, int out_size, void* d_ws, size_t ws_size,
                              hipStream_t stream) {
    const float* x_drug = (const float*)d_in[0];
    const float* x_dis  = (const float*)d_in[1];
    const float* W      = (const float*)d_in[2];   // [4,128,128]
    const float* b      = (const float*)d_in[3];   // [4,128]
    const float* pa     = (const float*)d_in[4];   // [1]
    EdgePtrs ep;
    ep.src[0] = (const int*)d_in[5];  ep.dst[0] = (const int*)d_in[6];   // dd
    ep.src[1] = (const int*)d_in[7];  ep.dst[1] = (const int*)d_in[8];   // ds
    ep.src[2] = (const int*)d_in[9];  ep.dst[2] = (const int*)d_in[10];  // sd
    ep.src[3] = (const int*)d_in[11]; ep.dst[3] = (const int*)d_in[12];  // ss

    // workspace layout (bytes); no memset needed — all buffers fully written
    char* ws = (char*)d_ws;
    unsigned short* cnt2in = (unsigned short*)(ws + 0);         // [4][16][NB]
    unsigned short* cnt2o  = (unsigned short*)(ws + 6400000);   // [4][16][NB]
    float* coef     = (float*)(ws + 12800000);  // [4][NB]
    int*   offs     = (int*)(ws + 13600000);    // [4][NB+1]
    int*   chunksum = (int*)(ws + 14400064);    // [4][NCH]
    int2*  epack    = (int2*)(ws + 14401664);   // [4][EB] int2 (16 MB)
    unsigned short* xh = (unsigned short*)(ws + 30401664);  // fp16 x (25.6 MB)
    _Float16* Wb    = (_Float16*)(ws + 56001664); // 128 KB packed W
    // total ~56.1 MB

    k_cvt<<<12532, 256, 0, stream>>>(x_drug, x_dis, xh, W, Wb);
    k_hist<<<dim3(NCHK, NRG, 8), 256, 0, stream>>>(ep, cnt2in, cnt2o);
    k_scan1<<<dim3(NCH, 4), 512, 0, stream>>>(cnt2in, cnt2o, coef, offs, chunksum);
    k_scan2<<<1, 256, 0, stream>>>(chunksum);
    k_scan3<<<dim3(NCH, 4), 512, 0, stream>>>(offs, chunksum);
    k_fill3<<<dim3(NCHK, NRG, 4), 256, 0, stream>>>(ep, cnt2in, coef, offs, epack);
    k_gather<<<dim3(782, 4), 256, 0, stream>>>(
        xh, offs, epack, (unsigned short*)d_out);
    k_gemm<<<dim3(782, 2), 256, 0, stream>>>(
        (const _Float16*)d_out, Wb, b, pa, (float*)d_out);
}

// Round 18
// 217.686 us; speedup vs baseline: 1.5527x; 1.0806x over previous
//
#include <hip/hip_runtime.h>
#include <hip/hip_fp16.h>

// Node_Embedding: HeteroGraphConv(sum) of 4 GraphConv relations + PReLU.
// Pipeline (no global atomics, no memsets):
//   k_cvt (x->fp16 + W-pack) ; k_hist (chunk x range LDS u16 histograms) ;
//   k_scan1..3 (chunk-prefix + CSR offs + coef) ; k_fill3 (chunked LDS-cursor
//   counting sort, int2 (src,coef)) ; k_gather (src-range-blocked gather,
//   edges in-block sorted by (row, range) -> pipelined run iteration, 4 range
//   passes w/ block barrier) ; k_gemm (MFMA f16 + bias + PReLU).
// R15-R17 validated: range-blocking cut L2-miss traffic 372->147MB, killed
// write amplification, sorted runs + fewer passes cut overhead 130->96us.
// This round: NRGP 8->4 (runs lengthen to ~2.5) + 1-deep load pipeline in
// the run loop (hide x-load latency across edges within a run).

#define NB 50000   // nodes per type
#define EB 500000  // edges per relation
#define D  128
#define NCH 98     // ceil(NB/512)
#define CAP 1024   // gather LDS edge capacity (mean 640 per 64 rows)
#define NCHK 16    // edge chunks (CSR build)
#define CH2 15625  // (EB/NCHK)/2 int2 loads per chunk
#define NRG 4      // node ranges (CSR build)
#define FR 12500   // nodes per range (CSR build)
#define NRGP 4     // gather src-range passes
#define RQ 12500   // NB/NRGP

struct EdgePtrs { const int* src[4]; const int* dst[4]; };

typedef _Float16 f16x8 __attribute__((ext_vector_type(8)));
typedef float f32x4 __attribute__((ext_vector_type(4)));

__device__ inline float hlo(unsigned u) {
    return __half2float(__ushort_as_half((unsigned short)(u & 0xffffu)));
}
__device__ inline float hhi(unsigned u) {
    return __half2float(__ushort_as_half((unsigned short)(u >> 16)));
}

// x (fp32) -> fp16, float4/thread; last 32 blocks pack W into MFMA B-frags.
__global__ __launch_bounds__(256) void k_cvt(const float* __restrict__ xd,
                                             const float* __restrict__ xs,
                                             unsigned short* __restrict__ xh,
                                             const float* __restrict__ W,
                                             _Float16* __restrict__ Wb) {
    int bx = blockIdx.x;
    if (bx < 12500) {
        int i = bx * 256 + threadIdx.x;   // float4 index, 3.2M total
        const int half = NB * D / 4;
        const float* src = (i < half) ? xd : xs;
        int j = (i < half) ? i : i - half;
        float4 v = reinterpret_cast<const float4*>(src)[j];
        ushort4 o;
        o.x = __half_as_ushort(__float2half(v.x));
        o.y = __half_as_ushort(__float2half(v.y));
        o.z = __half_as_ushort(__float2half(v.z));
        o.w = __half_as_ushort(__float2half(v.w));
        reinterpret_cast<ushort4*>(xh)[i] = o;
    } else {
        int idx = (bx - 12500) * 256 + threadIdx.x;   // 8192 total
        int t = idx >> 12, jt = (idx >> 9) & 7, ks = (idx >> 6) & 7, l = idx & 63;
        int col = jt * 16 + (l & 15);
        int kb = ks * 32 + (l >> 4) * 8;
        _Float16 h[8];
#pragma unroll
        for (int m = 0; m < 8; ++m) {
            int k = kb + m;
            int r = (k < 128) ? t : (2 + t);
            h[m] = (_Float16)W[r * D * D + (k & 127) * D + col];
        }
        *reinterpret_cast<f16x8*>(Wb + (size_t)idx * 8) = *reinterpret_cast<f16x8*>(h);
    }
}

// Chunked LDS histogram. Block (chunk, range, z) with z = io*4 + rel.
__global__ __launch_bounds__(256) void k_hist(EdgePtrs ep,
                                              unsigned short* __restrict__ cnt2in,
                                              unsigned short* __restrict__ cnt2o) {
    __shared__ unsigned pk[FR / 2];   // packed u16 pairs, 25 KB
    const int chunk = blockIdx.x, range = blockIdx.y;
    const int rel = blockIdx.z & 3, io = blockIdx.z >> 2;
    const int lo = range * FR;
    const int* arr = io ? ep.src[rel] : ep.dst[rel];
    for (int i = threadIdx.x; i < FR / 2; i += 256) pk[i] = 0;
    __syncthreads();
    const int2* a2 = reinterpret_cast<const int2*>(arr) + (size_t)chunk * CH2;
    for (int i = threadIdx.x; i < CH2; i += 256) {
        int2 v = a2[i];
        int n0 = v.x - lo;
        if ((unsigned)n0 < (unsigned)FR) atomicAdd(&pk[n0 >> 1], 1u << (16 * (n0 & 1)));
        int n1 = v.y - lo;
        if ((unsigned)n1 < (unsigned)FR) atomicAdd(&pk[n1 >> 1], 1u << (16 * (n1 & 1)));
    }
    __syncthreads();
    unsigned short* out = io ? cnt2o : cnt2in;
    unsigned* dst = reinterpret_cast<unsigned*>(out + ((size_t)(rel * NCHK + chunk)) * NB);
    for (int i = threadIdx.x; i < FR / 2; i += 256) dst[lo / 2 + i] = pk[i];
}

// Phase 1: per node — chunk-prefix cnt2in in place (u16), outdeg -> coef,
// then per-512-node exclusive block scan of total in-degree.
__global__ __launch_bounds__(512) void k_scan1(unsigned short* __restrict__ cnt2in,
                                               const unsigned short* __restrict__ cnt2o,
                                               float* __restrict__ coef,
                                               int* __restrict__ offs,
                                               int* __restrict__ chunksum) {
    int r = blockIdx.y, c = blockIdx.x, t = threadIdx.x;
    int node = c * 512 + t;
    int v = 0;
    if (node < NB) {
        int tin = 0;
#pragma unroll
        for (int k = 0; k < NCHK; ++k) {
            size_t idx = ((size_t)(r * NCHK + k)) * NB + node;
            int cc = cnt2in[idx];
            cnt2in[idx] = (unsigned short)tin;   // exclusive chunk prefix
            tin += cc;
        }
        v = tin;
        int tout = 0;
#pragma unroll
        for (int k = 0; k < NCHK; ++k)
            tout += cnt2o[((size_t)(r * NCHK + k)) * NB + node];
        coef[r * NB + node] = rsqrtf((float)(tout > 1 ? tout : 1));
    }
    __shared__ int sh[512];
    sh[t] = v;
    __syncthreads();
    for (int off = 1; off < 512; off <<= 1) {
        int u = (t >= off) ? sh[t - off] : 0;
        __syncthreads();
        sh[t] += u;
        __syncthreads();
    }
    int incl = sh[t];
    if (node < NB) offs[r * (NB + 1) + node] = incl - v;  // local exclusive
    if (t == 511) chunksum[r * NCH + c] = incl;
}

// Phase 2: exclusive scan of the NCH chunk totals per relation (wave r).
__global__ __launch_bounds__(256) void k_scan2(int* __restrict__ chunksum) {
    int r = threadIdx.x >> 6, lane = threadIdx.x & 63;
    int* cs = chunksum + r * NCH;
    int s0 = cs[lane];
    int s1 = (64 + lane < NCH) ? cs[64 + lane] : 0;
    int x = s0;
    for (int d = 1; d < 64; d <<= 1) { int u = __shfl_up(x, d, 64); if (lane >= d) x += u; }
    int tot0 = __shfl(x, 63, 64);
    int y = s1;
    for (int d = 1; d < 64; d <<= 1) { int u = __shfl_up(y, d, 64); if (lane >= d) y += u; }
    y += tot0;
    cs[lane] = x - s0;
    if (64 + lane < NCH) cs[64 + lane] = y - s1;
}

// Phase 3: add chunk base; offs[NB] = EB.
__global__ __launch_bounds__(512) void k_scan3(int* __restrict__ offs,
                                               const int* __restrict__ chunksum) {
    int r = blockIdx.y, c = blockIdx.x, t = threadIdx.x;
    int node = c * 512 + t;
    if (node < NB)
        offs[r * (NB + 1) + node] += chunksum[r * NCH + c];
    if (c == NCH - 1 && t == 0) offs[r * (NB + 1) + NB] = EB;
}

// Chunked counting-sort placement: int2 (src, coef) payload.
__global__ __launch_bounds__(256) void k_fill3(EdgePtrs ep,
                                               const unsigned short* __restrict__ cnt2in,
                                               const float* __restrict__ coef,
                                               const int* __restrict__ offs,
                                               int2* __restrict__ epack) {
    __shared__ int cur[FR];           // 50 KB
    const int chunk = blockIdx.x, range = blockIdx.y, rel = blockIdx.z;
    const int lo = range * FR;
    const unsigned short* pre = cnt2in + ((size_t)(rel * NCHK + chunk)) * NB;
    for (int i = threadIdx.x; i < FR; i += 256)
        cur[i] = offs[rel * (NB + 1) + lo + i] + pre[lo + i];
    __syncthreads();
    const int2* d2p = reinterpret_cast<const int2*>(ep.dst[rel]) + (size_t)chunk * CH2;
    const int2* s2p = reinterpret_cast<const int2*>(ep.src[rel]) + (size_t)chunk * CH2;
    const float* cf = coef + rel * NB;
    int2* epk = epack + (size_t)rel * EB;
    for (int i = threadIdx.x; i < CH2; i += 256) {
        int2 d2 = d2p[i];
        int2 s2 = s2p[i];
        int n0 = d2.x - lo;
        if ((unsigned)n0 < (unsigned)FR) {
            int pos = atomicAdd(&cur[n0], 1);
            epk[pos] = make_int2(s2.x, __float_as_int(cf[s2.x]));
        }
        int n1 = d2.y - lo;
        if ((unsigned)n1 < (unsigned)FR) {
            int pos = atomicAdd(&cur[n1], 1);
            epk[pos] = make_int2(s2.y, __float_as_int(cf[s2.y]));
        }
    }
}

#define FMA8A(c, rv, A)                                                        \
    {                                                                          \
        A[0] = fmaf(hlo(rv.x), c, A[0]); A[1] = fmaf(hhi(rv.x), c, A[1]);      \
        A[2] = fmaf(hlo(rv.y), c, A[2]); A[3] = fmaf(hhi(rv.y), c, A[3]);      \
        A[4] = fmaf(hlo(rv.z), c, A[4]); A[5] = fmaf(hhi(rv.z), c, A[5]);      \
        A[6] = fmaf(hlo(rv.w), c, A[6]); A[7] = fmaf(hhi(rv.w), c, A[7]);      \
    }

// Src-range-blocked gather, edges in-block sorted by (row, range).
// Block = 64 dst rows x ONE relation (blockIdx.y: t = y>>1, h = y&1).
// Staging: count (row,range) -> per-row run table -> scatter sorted.
// Pass loop: pipelined iteration over each row's range-r run (load edge i+1
// before FMAs of edge i), barrier per pass.
__global__ __launch_bounds__(256, 8) void k_gather(
    const unsigned short* __restrict__ xh,  // [2][NB][D] fp16: drug then dis
    const int* __restrict__ offs, const int2* __restrict__ epack,
    unsigned short* __restrict__ agg) {     // [2*NB][256] fp16 (aliases d_out)
    __shared__ int2 ebuf[CAP];              // 8 KB (sorted)
    __shared__ unsigned short key[CAP];     // 2 KB (row*NRGP+range per edge)
    __shared__ int soff[65];
    __shared__ int cnt[64 * NRGP];          // counts -> scatter cursors
    __shared__ int runstart[64 * (NRGP + 1)]; // run boundaries
    const int t = blockIdx.y >> 1, h = blockIdx.y & 1;
    const int rel = h ? (2 + t) : t;
    const int row0 = blockIdx.x * 64;
    const int tid = threadIdx.x;
    const int g = tid >> 4, l16 = tid & 15;
    const int cbase = l16 * 8;              // this lane's 8 fp16 columns
    const unsigned short* x = xh + (size_t)(rel >= 2 ? NB * D : 0);
    const int2* epk = epack + (size_t)rel * EB;

    if (tid < 65) {
        int idx = row0 + tid; if (idx > NB) idx = NB;
        soff[tid] = offs[rel * (NB + 1) + idx];
    }
    for (int i = tid; i < 64 * NRGP; i += 256) cnt[i] = 0;
    __syncthreads();

    const int base = soff[0];
    const int tot0 = soff[64] - base;
    const int tot = tot0 < CAP ? tot0 : CAP;

    // pass A: count (row, range); row via binary search over soff
    for (int i = tid; i < tot; i += 256) {
        int2 e = epk[base + i];
        int rng = (int)((unsigned)e.x / RQ);
        int lo = 0, hi = 64;
        while (hi - lo > 1) {
            int mid = (lo + hi) >> 1;
            if (soff[mid] - base <= i) lo = mid; else hi = mid;
        }
        int k = lo * NRGP + rng;
        key[i] = (unsigned short)k;
        atomicAdd(&cnt[k], 1);
    }
    __syncthreads();

    // per-row exclusive prefix over ranges -> run table + scatter cursors
    if (tid < 64) {
        int run = soff[tid] - base; if (run > CAP) run = CAP;
        for (int r = 0; r < NRGP; ++r) {
            int c = cnt[tid * NRGP + r];
            runstart[tid * (NRGP + 1) + r] = run;
            cnt[tid * NRGP + r] = run;
            run += c;
        }
        runstart[tid * (NRGP + 1) + NRGP] = run;
    }
    __syncthreads();

    // pass B: scatter into sorted order (re-read epk; L2-hot)
    for (int i = tid; i < tot; i += 256) {
        int2 e = epk[base + i];
        int pos = atomicAdd(&cnt[key[i]], 1);
        ebuf[pos] = e;
    }
    __syncthreads();

    // per-row segment bounds (group-uniform)
    int glo[4], ghi0[4];
    float dinv[4];
#pragma unroll
    for (int rr = 0; rr < 4; ++rr) {
        glo[rr]  = soff[g * 4 + rr] - base;
        ghi0[rr] = soff[g * 4 + rr + 1] - base;
        int dg = ghi0[rr] - glo[rr];
        dinv[rr] = rsqrtf((float)(dg > 1 ? dg : 1));
    }

    float racc[4][8] = {};

    // ---- range passes: pipelined run iteration ----
    for (int r = 0; r < NRGP; ++r) {
#pragma unroll
        for (int rr = 0; rr < 4; ++rr) {
            int row = g * 4 + rr;
            int s = runstart[row * (NRGP + 1) + r];
            int e_ = runstart[row * (NRGP + 1) + r + 1];
            if (s < e_) {
                int2 e0 = ebuf[s];
                float c0 = __int_as_float(e0.y);
                uint4 rv0 = *reinterpret_cast<const uint4*>(
                    x + ((unsigned)e0.x * D + cbase));
                for (int i = s + 1; i < e_; ++i) {
                    int2 e1 = ebuf[i];
                    float c1 = __int_as_float(e1.y);
                    uint4 rv1 = *reinterpret_cast<const uint4*>(
                        x + ((unsigned)e1.x * D + cbase));
                    FMA8A(c0, rv0, racc[rr]);
                    c0 = c1; rv0 = rv1;
                }
                FMA8A(c0, rv0, racc[rr]);
            }
        }
        __syncthreads();
    }

    // rare overflow tail (window beyond CAP) straight from global, unsorted
#pragma unroll
    for (int rr = 0; rr < 4; ++rr) {
        int st = glo[rr] > CAP ? glo[rr] : CAP;
        for (int i = st; i < ghi0[rr]; ++i) {
            int2 e = epk[base + i];
            float c = __int_as_float(e.y);
            uint4 rv = *reinterpret_cast<const uint4*>(
                x + ((unsigned)e.x * D + cbase));
            FMA8A(c, rv, racc[rr]);
        }
    }

    // scale + store fp16 half-rows (256B contiguous per row per block-half)
#pragma unroll
    for (int rr = 0; rr < 4; ++rr) {
        int row = row0 + g * 4 + rr;
        if (row < NB) {
            float di = dinv[rr];
            unsigned q[4];
#pragma unroll
            for (int k2 = 0; k2 < 4; ++k2) {
                unsigned lo2 = __half_as_ushort(__float2half(racc[rr][2 * k2] * di));
                unsigned hi2 = __half_as_ushort(__float2half(racc[rr][2 * k2 + 1] * di));
                q[k2] = lo2 | (hi2 << 16);
            }
            *reinterpret_cast<uint4*>(
                agg + ((size_t)(t * NB + row) * 256 + h * 128 + cbase)) =
                make_uint4(q[0], q[1], q[2], q[3]);
        }
    }
}

// Dense MFMA GEMM: out[r][j] = prelu(sum_k agg[r][k] * Wcat_t[k][j] + bias).
__global__ __launch_bounds__(256) void k_gemm(
    const _Float16* agg,                    // aliases out
    const _Float16* __restrict__ Wb,
    const float* __restrict__ b, const float* __restrict__ prelu_a,
    float* out) {
    const int t = blockIdx.y;
    const int tid = threadIdx.x, w = tid >> 6, l = tid & 63;
    const int rbase = t * NB + blockIdx.x * 64 + w * 16;
    const int rmax = t * NB + NB - 1;
    const int lk = (l >> 4) * 8;
    f32x4 acc[8] = {};
    const f16x8* wb = reinterpret_cast<const f16x8*>(Wb + (size_t)t * 32768);
    int ra = rbase + (l & 15); if (ra > rmax) ra = rmax;
    const _Float16* ap = agg + (size_t)ra * 256 + lk;
#pragma unroll
    for (int ks = 0; ks < 8; ++ks) {
        f16x8 a = *reinterpret_cast<const f16x8*>(ap + ks * 32);
#pragma unroll
        for (int jt = 0; jt < 8; ++jt) {
            f16x8 bf = wb[(jt * 8 + ks) * 64 + l];
            acc[jt] = __builtin_amdgcn_mfma_f32_16x16x32_f16(a, bf, acc[jt], 0, 0, 0);
        }
    }
    float pa = prelu_a[0];
    const int rowoff = (l >> 4) * 4;
#pragma unroll
    for (int jt = 0; jt < 8; ++jt) {
        int col = jt * 16 + (l & 15);
        float bs = b[t * D + col] + b[(2 + t) * D + col];
#pragma unroll
        for (int m = 0; m < 4; ++m) {
            int grow = rbase + rowoff + m;
            if (grow <= rmax) {
                float v = acc[jt][m] + bs;
                v = v >= 0.f ? v : pa * v;
                out[(size_t)grow * D + col] = v;
            }
        }
    }
}

extern "C" void kernel_launch(void* const* d_in, const int* in_sizes, int n_in,
                              void* d_out, int out_size, void* d_ws, size_t ws_size,
                              hipStream_t stream) {
    const float* x_drug = (const float*)d_in[0];
    const float* x_dis  = (const float*)d_in[1];
    const float* W      = (const float*)d_in[2];   // [4,128,128]
    const float* b      = (const float*)d_in[3];   // [4,128]
    const float* pa     = (const float*)d_in[4];   // [1]
    EdgePtrs ep;
    ep.src[0] = (const int*)d_in[5];  ep.dst[0] = (const int*)d_in[6];   // dd
    ep.src[1] = (const int*)d_in[7];  ep.dst[1] = (const int*)d_in[8];   // ds
    ep.src[2] = (const int*)d_in[9];  ep.dst[2] = (const int*)d_in[10];  // sd
    ep.src[3] = (const int*)d_in[11]; ep.dst[3] = (const int*)d_in[12];  // ss

    // workspace layout (bytes); no memset needed — all buffers fully written
    char* ws = (char*)d_ws;
    unsigned short* cnt2in = (unsigned short*)(ws + 0);         // [4][16][NB]
    unsigned short* cnt2o  = (unsigned short*)(ws + 6400000);   // [4][16][NB]
    float* coef     = (float*)(ws + 12800000);  // [4][NB]
    int*   offs     = (int*)(ws + 13600000);    // [4][NB+1]
    int*   chunksum = (int*)(ws + 14400064);    // [4][NCH]
    int2*  epack    = (int2*)(ws + 14401664);   // [4][EB] int2 (16 MB)
    unsigned short* xh = (unsigned short*)(ws + 30401664);  // fp16 x (25.6 MB)
    _Float16* Wb    = (_Float16*)(ws + 56001664); // 128 KB packed W
    // total ~56.1 MB

    k_cvt<<<12532, 256, 0, stream>>>(x_drug, x_dis, xh, W, Wb);
    k_hist<<<dim3(NCHK, NRG, 8), 256, 0, stream>>>(ep, cnt2in, cnt2o);
    k_scan1<<<dim3(NCH, 4), 512, 0, stream>>>(cnt2in, cnt2o, coef, offs, chunksum);
    k_scan2<<<1, 256, 0, stream>>>(chunksum);
    k_scan3<<<dim3(NCH, 4), 512, 0, stream>>>(offs, chunksum);
    k_fill3<<<dim3(NCHK, NRG, 4), 256, 0, stream>>>(ep, cnt2in, coef, offs, epack);
    k_gather<<<dim3(782, 4), 256, 0, stream>>>(
        xh, offs, epack, (unsigned short*)d_out);
    k_gemm<<<dim3(782, 2), 256, 0, stream>>>(
        (const _Float16*)d_out, Wb, b, pa, (float*)d_out);
}